// Round 1
// baseline (1013.311 us; speedup 1.0000x reference)
//
#include <hip/hip_runtime.h>
#include <math.h>

#define Nn 30000
#define RR 3
#define EE 80000
#define MT_M 235      // ceil(Nn/128)

#define SAP 72        // padded LDS row stride (bf16 elems) for staged tiles
#define EP_LD 68      // per-wave epilogue scratch stride (floats)
#define KBIG 0x40000000

typedef __attribute__((ext_vector_type(8))) short bf16x8;
typedef __attribute__((ext_vector_type(4))) float f32x4;

__device__ __forceinline__ unsigned short f2bf(float f) {
    union { float f; unsigned u; } v; v.f = f;
    unsigned r = v.u + 0x7fff + ((v.u >> 16) & 1);
    return (unsigned short)(r >> 16);
}
__device__ __forceinline__ float bf2f(short h) {
    union { unsigned u; float f; } v;
    v.u = ((unsigned)(unsigned short)h) << 16;
    return v.f;
}
__device__ __forceinline__ float fast_tanh(float x) {
    float e = __expf(2.f * x);
    return 1.f - 2.f / (e + 1.f);
}
__device__ __forceinline__ void unpack8(uint4 u, float* f) {
    union { unsigned u; float f; } a;
    a.u = u.x << 16;          f[0] = a.f;
    a.u = u.x & 0xffff0000u;  f[1] = a.f;
    a.u = u.y << 16;          f[2] = a.f;
    a.u = u.y & 0xffff0000u;  f[3] = a.f;
    a.u = u.z << 16;          f[4] = a.f;
    a.u = u.z & 0xffff0000u;  f[5] = a.f;
    a.u = u.w << 16;          f[6] = a.f;
    a.u = u.w & 0xffff0000u;  f[7] = a.f;
}

// ---------------------------------------------------------------------------
// LDS-staged MFMA GEMM core (128x128 tile, BK=64, 4 waves x 64x64).
// ---------------------------------------------------------------------------
__device__ __forceinline__ void mfma_core(
    const short* __restrict__ A, int lda,
    const short* __restrict__ A2, int lda2, int ksplit,
    const short* __restrict__ Bt,
    int M, int K, int m0, int n0,
    short* As, short* Bs, f32x4 (&acc)[4][4])
{
    const int t = threadIdx.x;
    const int srow = t >> 3;          // 0..31
    const int scol = (t & 7) << 3;    // 0..56 step 8
    const int lane = t & 63;
    const int wave = t >> 6;
    const int wm = (wave >> 1) << 6;
    const int wn = (wave & 1) << 6;
    const int fr = lane & 15;
    const int quad = lane >> 4;

    for (int k0 = 0; k0 < K; k0 += 64) {
        const short* Abase; int kk0, ldax;
        if (k0 < ksplit) { Abase = A;  kk0 = k0;          ldax = lda;  }
        else             { Abase = A2; kk0 = k0 - ksplit; ldax = lda2; }
        #pragma unroll
        for (int rr = 0; rr < 4; rr++) {
            int r = srow + rr * 32;
            int gr = m0 + r;
            bf16x8 va = {0, 0, 0, 0, 0, 0, 0, 0};
            if (gr < M) va = *(const bf16x8*)(Abase + (size_t)gr * ldax + kk0 + scol);
            *(bf16x8*)(As + r * SAP + scol) = va;
        }
        #pragma unroll
        for (int rr = 0; rr < 4; rr++) {
            int r = srow + rr * 32;
            bf16x8 vb = *(const bf16x8*)(Bt + (size_t)(n0 + r) * K + k0 + scol);
            *(bf16x8*)(Bs + r * SAP + scol) = vb;
        }
        __syncthreads();
        #pragma unroll
        for (int kc = 0; kc < 2; kc++) {
            bf16x8 af[4], bfr[4];
            #pragma unroll
            for (int i = 0; i < 4; i++)
                af[i] = *(const bf16x8*)(As + (wm + i * 16 + fr) * SAP + kc * 32 + quad * 8);
            #pragma unroll
            for (int i = 0; i < 4; i++)
                bfr[i] = *(const bf16x8*)(Bs + (wn + i * 16 + fr) * SAP + kc * 32 + quad * 8);
            #pragma unroll
            for (int mi = 0; mi < 4; mi++)
                #pragma unroll
                for (int ni = 0; ni < 4; ni++)
                    acc[mi][ni] = __builtin_amdgcn_mfma_f32_16x16x32_bf16(
                        af[mi], bfr[ni], acc[mi][ni], 0, 0, 0);
        }
        __syncthreads();
    }
}

// General GEMM: C = act(A @ Bt^T + bias). Wave-private LDS repack epilogue.
__global__ __launch_bounds__(256) void gemm_mfma(
    const short* __restrict__ A, int lda,
    const short* __restrict__ A2, int lda2, int ksplit,
    const short* __restrict__ Bt, const float* __restrict__ bias,
    float* __restrict__ C, int ldc, short* __restrict__ Cbf, int ldcbf,
    int M, int K, int act)
{
    __shared__ short As[128 * SAP];
    __shared__ short Bs[128 * SAP];
    f32x4 acc[4][4];
    #pragma unroll
    for (int i = 0; i < 4; i++)
        #pragma unroll
        for (int j = 0; j < 4; j++) acc[i][j] = (f32x4){0.f, 0.f, 0.f, 0.f};
    int m0 = blockIdx.y * 128, n0 = blockIdx.x * 128;
    mfma_core(A, lda, A2, lda2, ksplit, Bt, M, K, m0, n0, As, Bs, acc);

    const int t = threadIdx.x;
    const int lane = t & 63, wave = t >> 6;
    const int wm = (wave >> 1) << 6, wn = (wave & 1) << 6;
    const int fr = lane & 15, quad = lane >> 4;
    float* ws = (float*)As + wave * 16 * EP_LD;   // wave-private (post-barrier)
    const int rrow = lane >> 2;
    const int cseg = (lane & 3) << 4;
    #pragma unroll
    for (int mi = 0; mi < 4; mi++) {
        #pragma unroll
        for (int ni = 0; ni < 4; ni++)
            #pragma unroll
            for (int reg = 0; reg < 4; reg++)
                ws[(quad * 4 + reg) * EP_LD + ni * 16 + fr] = acc[mi][ni][reg];
        int gr = m0 + wm + mi * 16 + rrow;
        if (gr >= M) continue;
        int gc = n0 + wn + cseg;
        float vals[16];
        #pragma unroll
        for (int j = 0; j < 16; j++) {
            float v = ws[rrow * EP_LD + cseg + j] + bias[gc + j];
            if (act == 1) v = (v >= 0.f) ? v : 0.01f * v;
            vals[j] = v;
        }
        if (C) {
            float* cp = C + (size_t)gr * ldc + gc;
            #pragma unroll
            for (int j4 = 0; j4 < 4; j4++)
                *(float4*)(cp + j4 * 4) = make_float4(vals[j4 * 4], vals[j4 * 4 + 1],
                                                      vals[j4 * 4 + 2], vals[j4 * 4 + 3]);
        }
        if (Cbf) {
            unsigned pk[8];
            #pragma unroll
            for (int j2 = 0; j2 < 8; j2++)
                pk[j2] = ((unsigned)f2bf(vals[2 * j2 + 1]) << 16) | (unsigned)f2bf(vals[2 * j2]);
            unsigned* bp = (unsigned*)(Cbf + (size_t)gr * ldcbf + gc);
            *(uint4*)bp       = make_uint4(pk[0], pk[1], pk[2], pk[3]);
            *(uint4*)(bp + 4) = make_uint4(pk[4], pk[5], pk[6], pk[7]);
        }
    }
}

// ---------------------------------------------------------------------------
// Fused q|k|v (3 relations) + Ws GEMM, register-resident version.
// K = 128 fits entirely in registers: B-fragments (one 128-col tile of Wt)
// persist across 5 row panels; A-fragments loaded straight from global.
// No LDS, no barriers. Swapped-operand MFMA (mfma(b, a, acc)) puts 4
// CONSECUTIVE output columns of one row in each lane's f32x4 -> direct
// bf16 stores, no LDS repack.
//   t = blockIdx.x (0..38): t<36 -> qkv3[r=t/12][gr][(t%12)*128+..]
//                           t>=36 -> Ubf[gr][(t-36)*128+..]
// ---------------------------------------------------------------------------
__global__ __launch_bounds__(256, 2) void gemm_qkvs_v2(
    const short* __restrict__ A,       // h_bf [N,128]
    const short* __restrict__ Bt,      // qkvsWt [4992][128]
    const float* __restrict__ bias,    // [4992]
    short* __restrict__ qkv3, short* __restrict__ Ubf, int M)
{
    const int tt = blockIdx.x;           // tile 0..38
    const int n0 = tt * 128;
    const int lane = threadIdx.x & 63;
    const int wave = threadIdx.x >> 6;
    const int wm = (wave >> 1) << 6;
    const int wn = (wave & 1) << 6;
    const int fr = lane & 15;
    const int quad = lane >> 4;

    // persistent B fragments (64 VGPR), L2-hot (all of Bt = 1.28 MB)
    bf16x8 bq[4][4];
    #pragma unroll
    for (int ni = 0; ni < 4; ni++)
        #pragma unroll
        for (int kc = 0; kc < 4; kc++)
            bq[ni][kc] = *(const bf16x8*)(Bt + (size_t)(n0 + wn + ni * 16 + fr) * 128
                                              + kc * 32 + quad * 8);

    // per-lane bias: 4 consecutive output cols per ni
    float4 b4[4];
    #pragma unroll
    for (int ni = 0; ni < 4; ni++)
        b4[ni] = *(const float4*)(bias + n0 + wn + ni * 16 + quad * 4);

    // output base
    short* outBase;
    size_t rowStride, colOff;
    if (tt < 36) {
        int r3 = tt / 12;
        outBase = qkv3 + (size_t)r3 * Nn * 1536;
        rowStride = 1536;
        colOff = (size_t)(tt - r3 * 12) * 128;
    } else {
        outBase = Ubf;
        rowStride = 384;
        colOff = (size_t)(tt - 36) * 128;
    }

    #pragma unroll 1
    for (int p = 0; p < 5; p++) {
        const int m0 = (blockIdx.y * 5 + p) * 128;

        // A fragments straight from global (row-gathered 16B, L2/L3-resident)
        bf16x8 af[4][4];
        #pragma unroll
        for (int mi = 0; mi < 4; mi++) {
            int gr = m0 + wm + mi * 16 + fr;
            #pragma unroll
            for (int kc = 0; kc < 4; kc++) {
                bf16x8 v = {0, 0, 0, 0, 0, 0, 0, 0};
                if (gr < M) v = *(const bf16x8*)(A + (size_t)gr * 128 + kc * 32 + quad * 8);
                af[mi][kc] = v;
            }
        }

        f32x4 acc[4][4];
        #pragma unroll
        for (int i = 0; i < 4; i++)
            #pragma unroll
            for (int j = 0; j < 4; j++) acc[i][j] = (f32x4){0.f, 0.f, 0.f, 0.f};

        // swapped operands: D[n][m]; lane -> m = fr, n = quad*4+reg (per ni blk)
        #pragma unroll
        for (int kc = 0; kc < 4; kc++)
            #pragma unroll
            for (int mi = 0; mi < 4; mi++)
                #pragma unroll
                for (int ni = 0; ni < 4; ni++)
                    acc[mi][ni] = __builtin_amdgcn_mfma_f32_16x16x32_bf16(
                        bq[ni][kc], af[mi][kc], acc[mi][ni], 0, 0, 0);

        // direct epilogue: each lane's f32x4 = 4 consecutive cols of row gr
        #pragma unroll
        for (int mi = 0; mi < 4; mi++) {
            int gr = m0 + wm + mi * 16 + fr;
            if (gr >= M) continue;
            short* dst = outBase + (size_t)gr * rowStride + colOff + wn;
            #pragma unroll
            for (int ni = 0; ni < 4; ni++) {
                float v0 = acc[mi][ni][0] + b4[ni].x;
                float v1 = acc[mi][ni][1] + b4[ni].y;
                float v2 = acc[mi][ni][2] + b4[ni].z;
                float v3 = acc[mi][ni][3] + b4[ni].w;
                unsigned u0, u1;
                asm("v_cvt_pk_bf16_f32 %0, %1, %2" : "=v"(u0) : "v"(v0), "v"(v1));
                asm("v_cvt_pk_bf16_f32 %0, %1, %2" : "=v"(u1) : "v"(v2), "v"(v3));
                *(uint2*)(dst + ni * 16 + quad * 4) = make_uint2(u0, u1);
            }
        }
    }
}

// Gate (z = relation): Z = sigmoid([U_r|h] @ gW + gb); Hm_r = tanh(U_r)*Z + h*(1-Z).
// U read as bf16 (no fp32 U buffer).
__global__ __launch_bounds__(256) void gate_mfma(
    const short* __restrict__ Ubf,   // [N,384] bf16
    const short* __restrict__ Hbf,   // [N,128] bf16
    const short* __restrict__ gWt, const float* __restrict__ gb,
    const float* __restrict__ Hf,    // [N,128] fp32
    float* __restrict__ Hm, short* __restrict__ HmBf,   // [N,384]
    int M)
{
    __shared__ short As[128 * SAP];
    __shared__ short Bs[128 * SAP];
    f32x4 acc[4][4];
    #pragma unroll
    for (int i = 0; i < 4; i++)
        #pragma unroll
        for (int j = 0; j < 4; j++) acc[i][j] = (f32x4){0.f, 0.f, 0.f, 0.f};
    int r = blockIdx.z;
    int m0 = blockIdx.y * 128;
    mfma_core(Ubf + r * 128, 384, Hbf, 128, 128, gWt, M, 256, m0, 0, As, Bs, acc);

    const int t = threadIdx.x;
    const int lane = t & 63, wave = t >> 6;
    const int wm = (wave >> 1) << 6, wn = (wave & 1) << 6;
    const int fr = lane & 15, quad = lane >> 4;
    float* ws = (float*)As + wave * 16 * EP_LD;
    const int rrow = lane >> 2;
    const int cseg = (lane & 3) << 4;
    #pragma unroll
    for (int mi = 0; mi < 4; mi++) {
        #pragma unroll
        for (int ni = 0; ni < 4; ni++)
            #pragma unroll
            for (int reg = 0; reg < 4; reg++)
                ws[(quad * 4 + reg) * EP_LD + ni * 16 + fr] = acc[mi][ni][reg];
        int gr = m0 + wm + mi * 16 + rrow;
        if (gr >= M) continue;
        int gc = wn + cseg;
        const short* up = Ubf + (size_t)gr * 384 + r * 128 + gc;
        const float* hp = Hf + (size_t)gr * 128 + gc;
        float uv[16], hv[16];
        uint4 u0 = *(const uint4*)up;
        uint4 u1 = *(const uint4*)(up + 8);
        unpack8(u0, uv); unpack8(u1, uv + 8);
        #pragma unroll
        for (int j4 = 0; j4 < 4; j4++)
            *(float4*)(hv + j4 * 4) = *(const float4*)(hp + j4 * 4);
        float vals[16];
        #pragma unroll
        for (int j = 0; j < 16; j++) {
            float g = ws[rrow * EP_LD + cseg + j] + gb[gc + j];
            float z = 1.f / (1.f + __expf(-g));
            vals[j] = fast_tanh(uv[j]) * z + hv[j] * (1.f - z);
        }
        float* cp = Hm + (size_t)gr * 384 + r * 128 + gc;
        #pragma unroll
        for (int j4 = 0; j4 < 4; j4++)
            *(float4*)(cp + j4 * 4) = make_float4(vals[j4 * 4], vals[j4 * 4 + 1],
                                                  vals[j4 * 4 + 2], vals[j4 * 4 + 3]);
        unsigned pk[8];
        #pragma unroll
        for (int j2 = 0; j2 < 8; j2++)
            pk[j2] = ((unsigned)f2bf(vals[2 * j2 + 1]) << 16) | (unsigned)f2bf(vals[2 * j2]);
        unsigned* bp = (unsigned*)(HmBf + (size_t)gr * 384 + r * 128 + gc);
        *(uint4*)bp       = make_uint4(pk[0], pk[1], pk[2], pk[3]);
        *(uint4*)(bp + 4) = make_uint4(pk[4], pk[5], pk[6], pk[7]);
    }
}

// Semantic partial sums (no atomics).
__global__ __launch_bounds__(256) void semantic_mfma(
    const short* __restrict__ HmBf, const short* __restrict__ sW1t,
    const float* __restrict__ sb1, const float* __restrict__ sw2,
    float* __restrict__ partial, int M)
{
    __shared__ short As[128 * SAP];
    __shared__ short Bs[128 * SAP];
    __shared__ float red4[4];
    f32x4 acc[4][4];
    #pragma unroll
    for (int i = 0; i < 4; i++)
        #pragma unroll
        for (int j = 0; j < 4; j++) acc[i][j] = (f32x4){0.f, 0.f, 0.f, 0.f};
    int head = blockIdx.x, r = blockIdx.z;
    int m0 = blockIdx.y * 128, n0 = head * 128;
    mfma_core(HmBf + r * 128, 384, HmBf + r * 128, 384, KBIG, sW1t, M, 128, m0, n0, As, Bs, acc);
    const int t = threadIdx.x;
    const int lane = t & 63, wave = t >> 6;
    const int wm = (wave >> 1) << 6, wn = (wave & 1) << 6;
    const int fr = lane & 15, quad = lane >> 4;
    float local = 0.f;
    #pragma unroll
    for (int ni = 0; ni < 4; ni++) {
        int gc = n0 + wn + ni * 16 + fr;
        float b = sb1[gc], w2 = sw2[gc];
        #pragma unroll
        for (int mi = 0; mi < 4; mi++) {
            #pragma unroll
            for (int reg = 0; reg < 4; reg++) {
                int gr = m0 + wm + mi * 16 + quad * 4 + reg;
                if (gr >= M) continue;
                local += fast_tanh(acc[mi][ni][reg] + b) * w2;
            }
        }
    }
    #pragma unroll
    for (int off = 1; off < 64; off <<= 1) local += __shfl_xor(local, off);
    if (lane == 0) red4[wave] = local;
    __syncthreads();
    if (t == 0)
        partial[(head * 3 + r) * MT_M + blockIdx.y] = red4[0] + red4[1] + red4[2] + red4[3];
}

__global__ void reduce12_kernel(const float* __restrict__ partial, float* __restrict__ scores)
{
    int z = blockIdx.x;
    int lane = threadIdx.x;   // 64 threads
    float s = 0.f;
    for (int i = lane; i < MT_M; i += 64) s += partial[z * MT_M + i];
    #pragma unroll
    for (int off = 1; off < 64; off <<= 1) s += __shfl_xor(s, off);
    if (lane == 0) scores[z] = s;
}

__global__ void compute_w_kernel(const float* __restrict__ scores, float* __restrict__ w, float invN)
{
    if (blockIdx.x == 0 && threadIdx.x == 0) {
        float wr[3] = {0.f, 0.f, 0.f};
        for (int h = 0; h < 4; h++) {
            float s0 = scores[h * 3 + 0] * invN;
            float s1 = scores[h * 3 + 1] * invN;
            float s2 = scores[h * 3 + 2] * invN;
            float mx = fmaxf(s0, fmaxf(s1, s2));
            float e0 = __expf(s0 - mx), e1 = __expf(s1 - mx), e2 = __expf(s2 - mx);
            float inv = 1.f / (e0 + e1 + e2);
            wr[0] += 0.25f * e0 * inv;
            wr[1] += 0.25f * e1 * inv;
            wr[2] += 0.25f * e2 * inv;
        }
        w[0] = wr[0]; w[1] = wr[1]; w[2] = wr[2];
    }
}

__global__ void mix_kernel(const float* __restrict__ Hm, const float* __restrict__ w,
                           float* __restrict__ h, short* __restrict__ hbf, int total4)
{
    int i = blockIdx.x * blockDim.x + threadIdx.x;
    if (i >= total4) return;
    int n = i >> 5, c4 = (i & 31) << 2;
    const float* row = Hm + (size_t)n * 384 + c4;
    float4 a = *(const float4*)row;
    float4 b = *(const float4*)(row + 128);
    float4 c = *(const float4*)(row + 256);
    float w0 = w[0], w1 = w[1], w2 = w[2];
    float4 v = make_float4(w0 * a.x + w1 * b.x + w2 * c.x,
                           w0 * a.y + w1 * b.y + w2 * c.y,
                           w0 * a.z + w1 * b.z + w2 * c.z,
                           w0 * a.w + w1 * b.w + w2 * c.w);
    *(float4*)(h + (size_t)n * 128 + c4) = v;
    unsigned p0 = ((unsigned)f2bf(v.y) << 16) | (unsigned)f2bf(v.x);
    unsigned p1 = ((unsigned)f2bf(v.w) << 16) | (unsigned)f2bf(v.z);
    *(uint2*)(hbf + (size_t)n * 128 + c4) = make_uint2(p0, p1);
}

// --------------------------- conversions -----------------------------------
__global__ void convert_bf16_kernel(const float* __restrict__ src, unsigned* __restrict__ dst, int n_pairs)
{
    int i = blockIdx.x * blockDim.x + threadIdx.x;
    if (i >= n_pairs) return;
    float2 f = ((const float2*)src)[i];
    dst[i] = ((unsigned)f2bf(f.y) << 16) | (unsigned)f2bf(f.x);
}

__global__ void prep_global_kernel(const float* __restrict__ lin1_W, const float* __restrict__ lin2_W,
                                   short* __restrict__ lin1Wt, short* __restrict__ lin2Wt)
{
    int id = blockIdx.x * blockDim.x + threadIdx.x;
    if (id < 98304) {
        int n = id / 768, k = id % 768;
        lin1Wt[id] = (short)f2bf(lin1_W[k * 128 + n]);
    } else if (id < 114688) {
        int r = id - 98304;
        int n = r / 128, k = r % 128;
        lin2Wt[r] = (short)f2bf(lin2_W[k * 128 + n]);
    }
}

// Combined per-layer prep: qkvsWt [4992][128] (q|k|v for 3 relations + Ws),
// gWt [128][256], sW1t [512][128], qkvsB [4992].
__global__ void prep_layer_kernel(
    const float* __restrict__ Wq, const float* __restrict__ Wk, const float* __restrict__ Wv,
    const float* __restrict__ Ws, const float* __restrict__ bq, const float* __restrict__ bk,
    const float* __restrict__ bv, const float* __restrict__ bs,
    const float* __restrict__ gW, const float* __restrict__ sW1,
    short* __restrict__ qkvsWt, short* __restrict__ gWt,
    short* __restrict__ sW1t, float* __restrict__ qkvsB)
{
    const int S0 = 638976;             // 4992*128
    const int S1 = S0 + 32768;         // + gW
    const int S2 = S1 + 65536;         // + sW1
    const int S3 = S2 + 4992;          // + bias
    int id = blockIdx.x * blockDim.x + threadIdx.x;
    if (id < S0) {
        int n = id / 128, k = id - n * 128;
        float v;
        if (n < 4608) {
            int r = n / 1536, j = n - r * 1536;
            if (j < 512)       v = Wq[(size_t)r * 65536 + k * 512 + j];
            else if (j < 1024) v = Wk[(size_t)r * 65536 + k * 512 + (j - 512)];
            else               v = Wv[(size_t)r * 65536 + k * 512 + (j - 1024)];
        } else {
            int m = n - 4608;
            int r = m / 128, c = m - r * 128;
            v = Ws[(size_t)r * 16384 + k * 128 + c];
        }
        qkvsWt[id] = (short)f2bf(v);
    } else if (id < S1) {
        int q = id - S0;
        int n = q / 256, k = q - n * 256;
        gWt[q] = (short)f2bf(gW[k * 128 + n]);
    } else if (id < S2) {
        int q = id - S1;
        int h = q / 16384, rem = q - h * 16384;
        int n = rem / 128, k = rem - n * 128;
        sW1t[q] = (short)f2bf(sW1[(size_t)h * 16384 + k * 128 + n]);
    } else if (id < S3) {
        int q = id - S2;
        float v;
        if (q < 4608) {
            int r = q / 1536, j = q - r * 1536;
            if (j < 512)       v = bq[r * 512 + j];
            else if (j < 1024) v = bk[r * 512 + (j - 512)];
            else               v = bv[r * 512 + (j - 1024)];
        } else {
            v = bs[q - 4608];
        }
        qkvsB[q] = v;
    }
}

// --------------------------- CSR build (once) ------------------------------
__global__ void zero_i32_kernel(int* __restrict__ p, int n)
{
    int i = blockIdx.x * blockDim.x + threadIdx.x;
    if (i < n) p[i] = 0;
}

__global__ void hist3_kernel(const int* __restrict__ edges, int* __restrict__ cnt3)
{
    int i = blockIdx.x * blockDim.x + threadIdx.x;
    if (i >= 3 * EE) return;
    int r = i / EE, e = i - r * EE;
    int d = edges[(size_t)r * 2 * EE + EE + e];
    atomicAdd(&cnt3[r * Nn + d], 1);
}

__global__ __launch_bounds__(1024) void scan3_kernel(const int* __restrict__ cnt3,
                                                     int* __restrict__ rowptr3)
{
    __shared__ int part[1024];
    const int r = blockIdx.x;
    const int* cnt = cnt3 + r * Nn;
    int* rowptr = rowptr3 + r * (Nn + 1);
    int tid = threadIdx.x;
    int per = (Nn + 1023) >> 10;
    int base = tid * per;
    int s = 0;
    for (int i = 0; i < per; i++) {
        int idx = base + i;
        if (idx < Nn) s += cnt[idx];
    }
    part[tid] = s;
    __syncthreads();
    for (int off = 1; off < 1024; off <<= 1) {
        int val = (tid >= off) ? part[tid - off] : 0;
        __syncthreads();
        part[tid] += val;
        __syncthreads();
    }
    int excl = (tid == 0) ? 0 : part[tid - 1];
    for (int i = 0; i < per; i++) {
        int idx = base + i;
        if (idx < Nn) { rowptr[idx] = excl; excl += cnt[idx]; }
    }
    if (tid == 1023) rowptr[Nn] = part[1023];
}

__global__ void scatter3_kernel(const int* __restrict__ edges,
                                const int* __restrict__ rowptr3, int* __restrict__ fill3,
                                int* __restrict__ col3)
{
    int i = blockIdx.x * blockDim.x + threadIdx.x;
    if (i >= 3 * EE) return;
    int r = i / EE, e = i - r * EE;
    int src = edges[(size_t)r * 2 * EE + e];
    int d   = edges[(size_t)r * 2 * EE + EE + e];
    int pos = rowptr3[r * (Nn + 1) + d] + atomicAdd(&fill3[r * Nn + d], 1);
    col3[r * EE + pos] = src;
}

// --------------------------- attention (all 3 relations) -------------------
// One wave per (dst,relation). qkv3: [3][N][1536]. U in/out: bf16 [N,384].
__global__ __launch_bounds__(256) void attn_kernel(
    const short* __restrict__ qkv3,
    const int* __restrict__ rowptr3, const int* __restrict__ col3,
    short* __restrict__ Ubf)
{
    int wid = ((blockIdx.x * blockDim.x + threadIdx.x) >> 6);
    int lane = threadIdx.x & 63;
    if (wid >= 3 * Nn) return;
    int r = wid / Nn, n = wid - r * Nn;
    const short* qkv = qkv3 + (size_t)r * Nn * 1536;
    const int* rowptr = rowptr3 + r * (Nn + 1);
    const int* colb = col3 + r * EE;
    int beg = rowptr[n], end = rowptr[n + 1];

    uint4 qv = ((const uint4*)(qkv + (size_t)n * 1536))[lane];
    float qf[8];
    unpack8(qv, qf);

    float m = -INFINITY, s = 0.f;
    float acc[8] = {0.f, 0.f, 0.f, 0.f, 0.f, 0.f, 0.f, 0.f};
    const float scale = 0.088388347648318447f; // 1/sqrt(128)

    for (int i = beg; i < end; i++) {
        int src = colb[i];
        const short* base = qkv + (size_t)src * 1536;
        uint4 kv4 = ((const uint4*)(base + 512))[lane];
        uint4 vv4 = ((const uint4*)(base + 1024))[lane];
        float kf[8];
        unpack8(kv4, kf);
        float p = qf[0] * kf[0] + qf[1] * kf[1] + qf[2] * kf[2] + qf[3] * kf[3]
                + qf[4] * kf[4] + qf[5] * kf[5] + qf[6] * kf[6] + qf[7] * kf[7];
        p += __shfl_xor(p, 1);
        p += __shfl_xor(p, 2);
        p += __shfl_xor(p, 4);
        p += __shfl_xor(p, 8);
        float l = p * scale;
        float nm = fmaxf(m, l);
        float sc = __expf(m - nm);
        float pe = __expf(l - nm);
        float vf[8];
        unpack8(vv4, vf);
        s = s * sc + pe;
        #pragma unroll
        for (int j = 0; j < 8; j++) acc[j] = acc[j] * sc + pe * vf[j];
        m = nm;
    }

    float inv = (s > 0.f) ? 1.f / s : 0.f;
    #pragma unroll
    for (int j = 0; j < 8; j++) acc[j] *= inv;
    #pragma unroll
    for (int j = 0; j < 8; j++) acc[j] += __shfl_xor(acc[j], 16);
    #pragma unroll
    for (int j = 0; j < 8; j++) acc[j] += __shfl_xor(acc[j], 32);

    if (lane < 16) {
        short* urow = Ubf + (size_t)n * 384 + r * 128 + lane * 8;
        uint4 old = *(uint4*)urow;
        float sv[8];
        unpack8(old, sv);
        #pragma unroll
        for (int j = 0; j < 8; j++) sv[j] += 0.25f * acc[j];
        unsigned p0 = ((unsigned)f2bf(sv[1]) << 16) | (unsigned)f2bf(sv[0]);
        unsigned p1 = ((unsigned)f2bf(sv[3]) << 16) | (unsigned)f2bf(sv[2]);
        unsigned p2 = ((unsigned)f2bf(sv[5]) << 16) | (unsigned)f2bf(sv[4]);
        unsigned p3 = ((unsigned)f2bf(sv[7]) << 16) | (unsigned)f2bf(sv[6]);
        *(uint4*)urow = make_uint4(p0, p1, p2, p3);
    }
}

// --------------------------- classifier -----------------------------------
__global__ void clf_kernel(const float* __restrict__ t, const float* __restrict__ W,
                           const float* __restrict__ b, float* __restrict__ out, int M)
{
    int n = blockIdx.x * blockDim.x + threadIdx.x;
    if (n >= M) return;
    const float* row = t + (size_t)n * 128;
    float a0 = b[0], a1 = b[1];
    #pragma unroll
    for (int kk = 0; kk < 128; kk++) {
        float a = row[kk];
        a0 += a * W[kk * 2];
        a1 += a * W[kk * 2 + 1];
    }
    out[n * 2] = a0;
    out[n * 2 + 1] = a1;
}

// ---------------------------------------------------------------------------
extern "C" void kernel_launch(void* const* d_in, const int* in_sizes, int n_in,
                              void* d_out, int out_size, void* d_ws, size_t ws_size,
                              hipStream_t stream)
{
    const float* x      = (const float*)d_in[0];
    const int*   edges  = (const int*)d_in[1];
    const float* lin1_W = (const float*)d_in[2];
    const float* lin1_b = (const float*)d_in[3];
    const int L0 = 4, L1 = 17;
    const float* lin2_W = (const float*)d_in[30];
    const float* lin2_b = (const float*)d_in[31];
    const float* clf_W  = (const float*)d_in[32];
    const float* clf_b  = (const float*)d_in[33];
    float* out = (float*)d_out;

    char* w = (char*)d_ws;
    size_t off = 0;
    auto alloc = [&](size_t bytes) { void* p = w + off; off = (off + bytes + 255) & ~(size_t)255; return p; };
    float* h      = (float*)alloc((size_t)Nn * 128 * 4);     // 15.4 MB
    short* h_bf   = (short*)alloc((size_t)Nn * 128 * 2);     //  7.7 MB
    short* U_bf   = (short*)alloc((size_t)Nn * 384 * 2);     // 23.0 MB
    // BIG union region (276.5 MB): qkv3 [3][N][1536] bf16  <->  x_bf [N,768] bf16
    //                              <->  Hm [N,384] f32 + Hm_bf [N,384] bf16
    char* BIG     = (char*)alloc((size_t)3 * Nn * 1536 * 2);
    short* qkv3   = (short*)BIG;
    short* x_bf   = (short*)BIG;
    float* Hm     = (float*)BIG;
    short* Hm_bf  = (short*)(BIG + (size_t)Nn * 384 * 4);
    float* lin2o  = (float*)BIG;                              // lin2 out (post layer-2)
    short* lin1Wt = (short*)alloc((size_t)98304 * 2);
    short* lin2Wt = (short*)alloc((size_t)16384 * 2);
    short* qkvsWt = (short*)alloc((size_t)2 * 638976 * 2);
    short* gWt    = (short*)alloc((size_t)2 * 32768 * 2);
    short* sW1t   = (short*)alloc((size_t)2 * 65536 * 2);
    float* qkvsB  = (float*)alloc((size_t)2 * 4992 * 4);
    int* rowptr3  = (int*)alloc((size_t)3 * (Nn + 1) * 4);
    int* cnt3     = (int*)alloc((size_t)3 * Nn * 4);
    int* col3     = (int*)alloc((size_t)3 * EE * 4);
    float* partial = (float*)alloc((size_t)12 * MT_M * 4);
    float* scores = (float*)alloc(12 * 4);
    float* wmix   = (float*)alloc(3 * 4);

    const int MT = MT_M;    // 235
    dim3 blk(256);

    // ---- prep ----
    {
        int n_pairs = Nn * 768 / 2;
        convert_bf16_kernel<<<(n_pairs + 255) / 256, blk, 0, stream>>>(x, (unsigned*)x_bf, n_pairs);
        prep_global_kernel<<<(114688 + 255) / 256, blk, 0, stream>>>(lin1_W, lin2_W, lin1Wt, lin2Wt);
        for (int l = 0; l < 2; l++) {
            int base = (l == 0) ? L0 : L1;
            prep_layer_kernel<<<(742272 + 255) / 256, blk, 0, stream>>>(
                (const float*)d_in[base + 0], (const float*)d_in[base + 2], (const float*)d_in[base + 4],
                (const float*)d_in[base + 6], (const float*)d_in[base + 1], (const float*)d_in[base + 3],
                (const float*)d_in[base + 5], (const float*)d_in[base + 7],
                (const float*)d_in[base + 8], (const float*)d_in[base + 10],
                qkvsWt + (size_t)l * 638976, gWt + (size_t)l * 32768,
                sW1t + (size_t)l * 65536, qkvsB + (size_t)l * 4992);
        }
        zero_i32_kernel<<<(3 * Nn + 255) / 256, blk, 0, stream>>>(cnt3, 3 * Nn);
        hist3_kernel<<<(3 * EE + 255) / 256, blk, 0, stream>>>(edges, cnt3);
        scan3_kernel<<<3, 1024, 0, stream>>>(cnt3, rowptr3);
        zero_i32_kernel<<<(3 * Nn + 255) / 256, blk, 0, stream>>>(cnt3, 3 * Nn);
        scatter3_kernel<<<(3 * EE + 255) / 256, blk, 0, stream>>>(edges, rowptr3, cnt3, col3);
    }

    // lin1: h = lrelu(x @ lin1_W + b)   (x_bf in BIG; done before qkv overwrites)
    gemm_mfma<<<dim3(1, MT), blk, 0, stream>>>(
        x_bf, 768, x_bf, 768, KBIG, lin1Wt, lin1_b, h, 128, h_bf, 128, Nn, 768, 1);

    for (int l = 0; l < 2; l++) {
        int base = (l == 0) ? L0 : L1;
        const float* gb  = (const float*)d_in[base + 9];
        const float* sb1 = (const float*)d_in[base + 11];
        const float* sw2 = (const float*)d_in[base + 12];
        short* lqkvsWt = qkvsWt + (size_t)l * 638976;
        short* lgWt    = gWt + (size_t)l * 32768;
        short* lsW1t   = sW1t + (size_t)l * 65536;
        float* lqkvsB  = qkvsB + (size_t)l * 4992;

        // fused q|k|v (3 relations) + Ws -> qkv3 + U_bf  (register-resident GEMM)
        gemm_qkvs_v2<<<dim3(39, 47), blk, 0, stream>>>(
            h_bf, lqkvsWt, lqkvsB, qkv3, U_bf, Nn);

        // attention, all 3 relations: U += mean-head agg (in place, bf16)
        attn_kernel<<<(3 * Nn + 3) / 4, blk, 0, stream>>>(qkv3, rowptr3, col3, U_bf);

        // gate + combine (3 relations) -> Hm (fp32 + bf16)   [qkv3 dead now]
        gate_mfma<<<dim3(1, MT, 3), blk, 0, stream>>>(
            U_bf, h_bf, lgWt, gb, h, Hm, Hm_bf, Nn);

        // semantic attention
        semantic_mfma<<<dim3(4, MT, 3), blk, 0, stream>>>(Hm_bf, lsW1t, sb1, sw2, partial, Nn);
        reduce12_kernel<<<12, 64, 0, stream>>>(partial, scores);
        compute_w_kernel<<<1, 64, 0, stream>>>(scores, wmix, 1.f / (float)Nn);
        mix_kernel<<<(Nn * 32 + 255) / 256, blk, 0, stream>>>(Hm, wmix, h, h_bf, Nn * 32);
    }

    // lin2 + lrelu -> lin2o (BIG region, Hm dead after mix)
    gemm_mfma<<<dim3(1, MT), blk, 0, stream>>>(
        h_bf, 128, h_bf, 128, KBIG, lin2Wt, lin2_b, lin2o, 128, (short*)nullptr, 0, Nn, 128, 1);
    clf_kernel<<<(Nn + 255) / 256, blk, 0, stream>>>(lin2o, clf_W, clf_b, out, Nn);
}

// Round 2
// 1008.303 us; speedup vs baseline: 1.0050x; 1.0050x over previous
//
#include <hip/hip_runtime.h>
#include <math.h>

#define Nn 30000
#define RR 3
#define EE 80000
#define MT_M 235      // ceil(Nn/128)

#define SAP 72        // padded LDS row stride (bf16 elems) for staged tiles
#define EP_LD 68      // per-wave epilogue scratch stride (floats)
#define AS3 136       // v3 A-panel LDS row stride (128 + 8 pad, same 4-bank/row advance)
#define KBIG 0x40000000

typedef __attribute__((ext_vector_type(8))) short bf16x8;
typedef __attribute__((ext_vector_type(4))) float f32x4;

__device__ __forceinline__ unsigned short f2bf(float f) {
    union { float f; unsigned u; } v; v.f = f;
    unsigned r = v.u + 0x7fff + ((v.u >> 16) & 1);
    return (unsigned short)(r >> 16);
}
__device__ __forceinline__ float bf2f(short h) {
    union { unsigned u; float f; } v;
    v.u = ((unsigned)(unsigned short)h) << 16;
    return v.f;
}
__device__ __forceinline__ float fast_tanh(float x) {
    float e = __expf(2.f * x);
    return 1.f - 2.f / (e + 1.f);
}
__device__ __forceinline__ void unpack8(uint4 u, float* f) {
    union { unsigned u; float f; } a;
    a.u = u.x << 16;          f[0] = a.f;
    a.u = u.x & 0xffff0000u;  f[1] = a.f;
    a.u = u.y << 16;          f[2] = a.f;
    a.u = u.y & 0xffff0000u;  f[3] = a.f;
    a.u = u.z << 16;          f[4] = a.f;
    a.u = u.z & 0xffff0000u;  f[5] = a.f;
    a.u = u.w << 16;          f[6] = a.f;
    a.u = u.w & 0xffff0000u;  f[7] = a.f;
}

// ---------------------------------------------------------------------------
// LDS-staged MFMA GEMM core (128x128 tile, BK=64, 4 waves x 64x64).
// ---------------------------------------------------------------------------
__device__ __forceinline__ void mfma_core(
    const short* __restrict__ A, int lda,
    const short* __restrict__ A2, int lda2, int ksplit,
    const short* __restrict__ Bt,
    int M, int K, int m0, int n0,
    short* As, short* Bs, f32x4 (&acc)[4][4])
{
    const int t = threadIdx.x;
    const int srow = t >> 3;          // 0..31
    const int scol = (t & 7) << 3;    // 0..56 step 8
    const int lane = t & 63;
    const int wave = t >> 6;
    const int wm = (wave >> 1) << 6;
    const int wn = (wave & 1) << 6;
    const int fr = lane & 15;
    const int quad = lane >> 4;

    for (int k0 = 0; k0 < K; k0 += 64) {
        const short* Abase; int kk0, ldax;
        if (k0 < ksplit) { Abase = A;  kk0 = k0;          ldax = lda;  }
        else             { Abase = A2; kk0 = k0 - ksplit; ldax = lda2; }
        #pragma unroll
        for (int rr = 0; rr < 4; rr++) {
            int r = srow + rr * 32;
            int gr = m0 + r;
            bf16x8 va = {0, 0, 0, 0, 0, 0, 0, 0};
            if (gr < M) va = *(const bf16x8*)(Abase + (size_t)gr * ldax + kk0 + scol);
            *(bf16x8*)(As + r * SAP + scol) = va;
        }
        #pragma unroll
        for (int rr = 0; rr < 4; rr++) {
            int r = srow + rr * 32;
            bf16x8 vb = *(const bf16x8*)(Bt + (size_t)(n0 + r) * K + k0 + scol);
            *(bf16x8*)(Bs + r * SAP + scol) = vb;
        }
        __syncthreads();
        #pragma unroll
        for (int kc = 0; kc < 2; kc++) {
            bf16x8 af[4], bfr[4];
            #pragma unroll
            for (int i = 0; i < 4; i++)
                af[i] = *(const bf16x8*)(As + (wm + i * 16 + fr) * SAP + kc * 32 + quad * 8);
            #pragma unroll
            for (int i = 0; i < 4; i++)
                bfr[i] = *(const bf16x8*)(Bs + (wn + i * 16 + fr) * SAP + kc * 32 + quad * 8);
            #pragma unroll
            for (int mi = 0; mi < 4; mi++)
                #pragma unroll
                for (int ni = 0; ni < 4; ni++)
                    acc[mi][ni] = __builtin_amdgcn_mfma_f32_16x16x32_bf16(
                        af[mi], bfr[ni], acc[mi][ni], 0, 0, 0);
        }
        __syncthreads();
    }
}

// General GEMM: C = act(A @ Bt^T + bias). Wave-private LDS repack epilogue.
__global__ __launch_bounds__(256) void gemm_mfma(
    const short* __restrict__ A, int lda,
    const short* __restrict__ A2, int lda2, int ksplit,
    const short* __restrict__ Bt, const float* __restrict__ bias,
    float* __restrict__ C, int ldc, short* __restrict__ Cbf, int ldcbf,
    int M, int K, int act)
{
    __shared__ short As[128 * SAP];
    __shared__ short Bs[128 * SAP];
    f32x4 acc[4][4];
    #pragma unroll
    for (int i = 0; i < 4; i++)
        #pragma unroll
        for (int j = 0; j < 4; j++) acc[i][j] = (f32x4){0.f, 0.f, 0.f, 0.f};
    int m0 = blockIdx.y * 128, n0 = blockIdx.x * 128;
    mfma_core(A, lda, A2, lda2, ksplit, Bt, M, K, m0, n0, As, Bs, acc);

    const int t = threadIdx.x;
    const int lane = t & 63, wave = t >> 6;
    const int wm = (wave >> 1) << 6, wn = (wave & 1) << 6;
    const int fr = lane & 15, quad = lane >> 4;
    float* ws = (float*)As + wave * 16 * EP_LD;   // wave-private (post-barrier)
    const int rrow = lane >> 2;
    const int cseg = (lane & 3) << 4;
    #pragma unroll
    for (int mi = 0; mi < 4; mi++) {
        #pragma unroll
        for (int ni = 0; ni < 4; ni++)
            #pragma unroll
            for (int reg = 0; reg < 4; reg++)
                ws[(quad * 4 + reg) * EP_LD + ni * 16 + fr] = acc[mi][ni][reg];
        int gr = m0 + wm + mi * 16 + rrow;
        if (gr >= M) continue;
        int gc = n0 + wn + cseg;
        float vals[16];
        #pragma unroll
        for (int j = 0; j < 16; j++) {
            float v = ws[rrow * EP_LD + cseg + j] + bias[gc + j];
            if (act == 1) v = (v >= 0.f) ? v : 0.01f * v;
            vals[j] = v;
        }
        if (C) {
            float* cp = C + (size_t)gr * ldc + gc;
            #pragma unroll
            for (int j4 = 0; j4 < 4; j4++)
                *(float4*)(cp + j4 * 4) = make_float4(vals[j4 * 4], vals[j4 * 4 + 1],
                                                      vals[j4 * 4 + 2], vals[j4 * 4 + 3]);
        }
        if (Cbf) {
            unsigned pk[8];
            #pragma unroll
            for (int j2 = 0; j2 < 8; j2++)
                pk[j2] = ((unsigned)f2bf(vals[2 * j2 + 1]) << 16) | (unsigned)f2bf(vals[2 * j2]);
            unsigned* bp = (unsigned*)(Cbf + (size_t)gr * ldcbf + gc);
            *(uint4*)bp       = make_uint4(pk[0], pk[1], pk[2], pk[3]);
            *(uint4*)(bp + 4) = make_uint4(pk[4], pk[5], pk[6], pk[7]);
        }
    }
}

// ---------------------------------------------------------------------------
// Fused q|k|v (3 relations) + Ws GEMM, v3: panel-resident A.
// One block = one 128-row panel x 3 col-tiles. A staged into padded LDS ONCE
// (single barrier in the kernel), reused across tiles. B-tile fragments go
// global->registers (Bt = 1.28 MB, L2-hot). Epilogue = v1's wave-private LDS
// repack (separate scratch so the A panel survives) -> coalesced 16B stores.
//   tt = bx*3+j (0..38): tt<36 -> qkv3[r=tt/12][gr][(tt%12)*128+..]
//                        tt>=36 -> Ubf[gr][(tt-36)*128+..]
// ---------------------------------------------------------------------------
__global__ __launch_bounds__(256) void gemm_qkvs_v3(
    const short* __restrict__ A,       // h_bf [N,128]
    const short* __restrict__ Bt,      // qkvsWt [4992][128]
    const float* __restrict__ bias,    // [4992]
    short* __restrict__ qkv3, short* __restrict__ Ubf, int M)
{
    __shared__ short As[128 * AS3];            // 34.8 KB padded A panel
    __shared__ float ws4[4 * 16 * EP_LD];      // 17.4 KB wave-private repack scratch
    const int t = threadIdx.x;
    const int m0 = blockIdx.y * 128;

    // ---- stage A panel once: coalesced 256B global rows -> padded LDS ----
    {
        const int row0 = t >> 4;               // 0..15
        const int col  = (t & 15) << 3;        // 0..120 step 8
        #pragma unroll
        for (int rr = 0; rr < 8; rr++) {
            int r = row0 + rr * 16;
            int gr = m0 + r;
            bf16x8 va = {0, 0, 0, 0, 0, 0, 0, 0};
            if (gr < M) va = *(const bf16x8*)(A + (size_t)gr * 128 + col);
            *(bf16x8*)(As + r * AS3 + col) = va;
        }
    }
    __syncthreads();                            // the only barrier

    const int lane = t & 63, wave = t >> 6;
    const int wm = (wave >> 1) << 6, wn = (wave & 1) << 6;
    const int fr = lane & 15, quad = lane >> 4;
    float* ws = ws4 + wave * 16 * EP_LD;
    const int rrow = lane >> 2;
    const int cseg = (lane & 3) << 4;

    #pragma unroll 1
    for (int j = 0; j < 3; j++) {
        const int tt = blockIdx.x * 3 + j;      // 0..38
        const int n0 = tt * 128;

        // B-tile fragments: global (L2-hot) -> registers, 16 x 16B per lane
        bf16x8 bq[4][4];
        #pragma unroll
        for (int ni = 0; ni < 4; ni++)
            #pragma unroll
            for (int kc = 0; kc < 4; kc++)
                bq[ni][kc] = *(const bf16x8*)(Bt + (size_t)(n0 + wn + ni * 16 + fr) * 128
                                                  + kc * 32 + quad * 8);

        f32x4 acc[4][4];
        #pragma unroll
        for (int i = 0; i < 4; i++)
            #pragma unroll
            for (int jj = 0; jj < 4; jj++) acc[i][jj] = (f32x4){0.f, 0.f, 0.f, 0.f};

        #pragma unroll
        for (int kc = 0; kc < 4; kc++) {
            bf16x8 af[4];
            #pragma unroll
            for (int mi = 0; mi < 4; mi++)
                af[mi] = *(const bf16x8*)(As + (wm + mi * 16 + fr) * AS3 + kc * 32 + quad * 8);
            #pragma unroll
            for (int mi = 0; mi < 4; mi++)
                #pragma unroll
                for (int ni = 0; ni < 4; ni++)
                    acc[mi][ni] = __builtin_amdgcn_mfma_f32_16x16x32_bf16(
                        af[mi], bq[ni][kc], acc[mi][ni], 0, 0, 0);
        }

        // output routing for this tile
        short* outBase; size_t rowStride; int colOff;
        if (tt < 36) {
            int r3 = tt / 12;
            outBase = qkv3 + (size_t)r3 * Nn * 1536;
            rowStride = 1536;
            colOff = (tt - r3 * 12) * 128;
        } else {
            outBase = Ubf;
            rowStride = 384;
            colOff = (tt - 36) * 128;
        }

        // v1-style wave-private repack epilogue (no barrier needed)
        #pragma unroll
        for (int mi = 0; mi < 4; mi++) {
            #pragma unroll
            for (int ni = 0; ni < 4; ni++)
                #pragma unroll
                for (int reg = 0; reg < 4; reg++)
                    ws[(quad * 4 + reg) * EP_LD + ni * 16 + fr] = acc[mi][ni][reg];
            int gr = m0 + wm + mi * 16 + rrow;
            if (gr >= M) continue;
            int lc = wn + cseg;
            float vals[16];
            #pragma unroll
            for (int jj = 0; jj < 16; jj++)
                vals[jj] = ws[rrow * EP_LD + cseg + jj] + bias[n0 + lc + jj];
            unsigned pk[8];
            #pragma unroll
            for (int j2 = 0; j2 < 8; j2++)
                pk[j2] = ((unsigned)f2bf(vals[2 * j2 + 1]) << 16) | (unsigned)f2bf(vals[2 * j2]);
            unsigned* bp = (unsigned*)(outBase + (size_t)gr * rowStride + colOff + lc);
            *(uint4*)bp       = make_uint4(pk[0], pk[1], pk[2], pk[3]);
            *(uint4*)(bp + 4) = make_uint4(pk[4], pk[5], pk[6], pk[7]);
        }
    }
}

// Gate (z = relation): Z = sigmoid([U_r|h] @ gW + gb); Hm_r = tanh(U_r)*Z + h*(1-Z).
// U read as bf16 (no fp32 U buffer).
__global__ __launch_bounds__(256) void gate_mfma(
    const short* __restrict__ Ubf,   // [N,384] bf16
    const short* __restrict__ Hbf,   // [N,128] bf16
    const short* __restrict__ gWt, const float* __restrict__ gb,
    const float* __restrict__ Hf,    // [N,128] fp32
    float* __restrict__ Hm, short* __restrict__ HmBf,   // [N,384]
    int M)
{
    __shared__ short As[128 * SAP];
    __shared__ short Bs[128 * SAP];
    f32x4 acc[4][4];
    #pragma unroll
    for (int i = 0; i < 4; i++)
        #pragma unroll
        for (int j = 0; j < 4; j++) acc[i][j] = (f32x4){0.f, 0.f, 0.f, 0.f};
    int r = blockIdx.z;
    int m0 = blockIdx.y * 128;
    mfma_core(Ubf + r * 128, 384, Hbf, 128, 128, gWt, M, 256, m0, 0, As, Bs, acc);

    const int t = threadIdx.x;
    const int lane = t & 63, wave = t >> 6;
    const int wm = (wave >> 1) << 6, wn = (wave & 1) << 6;
    const int fr = lane & 15, quad = lane >> 4;
    float* ws = (float*)As + wave * 16 * EP_LD;
    const int rrow = lane >> 2;
    const int cseg = (lane & 3) << 4;
    #pragma unroll
    for (int mi = 0; mi < 4; mi++) {
        #pragma unroll
        for (int ni = 0; ni < 4; ni++)
            #pragma unroll
            for (int reg = 0; reg < 4; reg++)
                ws[(quad * 4 + reg) * EP_LD + ni * 16 + fr] = acc[mi][ni][reg];
        int gr = m0 + wm + mi * 16 + rrow;
        if (gr >= M) continue;
        int gc = wn + cseg;
        const short* up = Ubf + (size_t)gr * 384 + r * 128 + gc;
        const float* hp = Hf + (size_t)gr * 128 + gc;
        float uv[16], hv[16];
        uint4 u0 = *(const uint4*)up;
        uint4 u1 = *(const uint4*)(up + 8);
        unpack8(u0, uv); unpack8(u1, uv + 8);
        #pragma unroll
        for (int j4 = 0; j4 < 4; j4++)
            *(float4*)(hv + j4 * 4) = *(const float4*)(hp + j4 * 4);
        float vals[16];
        #pragma unroll
        for (int j = 0; j < 16; j++) {
            float g = ws[rrow * EP_LD + cseg + j] + gb[gc + j];
            float z = 1.f / (1.f + __expf(-g));
            vals[j] = fast_tanh(uv[j]) * z + hv[j] * (1.f - z);
        }
        float* cp = Hm + (size_t)gr * 384 + r * 128 + gc;
        #pragma unroll
        for (int j4 = 0; j4 < 4; j4++)
            *(float4*)(cp + j4 * 4) = make_float4(vals[j4 * 4], vals[j4 * 4 + 1],
                                                  vals[j4 * 4 + 2], vals[j4 * 4 + 3]);
        unsigned pk[8];
        #pragma unroll
        for (int j2 = 0; j2 < 8; j2++)
            pk[j2] = ((unsigned)f2bf(vals[2 * j2 + 1]) << 16) | (unsigned)f2bf(vals[2 * j2]);
        unsigned* bp = (unsigned*)(HmBf + (size_t)gr * 384 + r * 128 + gc);
        *(uint4*)bp       = make_uint4(pk[0], pk[1], pk[2], pk[3]);
        *(uint4*)(bp + 4) = make_uint4(pk[4], pk[5], pk[6], pk[7]);
    }
}

// Semantic partial sums (no atomics).
__global__ __launch_bounds__(256) void semantic_mfma(
    const short* __restrict__ HmBf, const short* __restrict__ sW1t,
    const float* __restrict__ sb1, const float* __restrict__ sw2,
    float* __restrict__ partial, int M)
{
    __shared__ short As[128 * SAP];
    __shared__ short Bs[128 * SAP];
    __shared__ float red4[4];
    f32x4 acc[4][4];
    #pragma unroll
    for (int i = 0; i < 4; i++)
        #pragma unroll
        for (int j = 0; j < 4; j++) acc[i][j] = (f32x4){0.f, 0.f, 0.f, 0.f};
    int head = blockIdx.x, r = blockIdx.z;
    int m0 = blockIdx.y * 128, n0 = head * 128;
    mfma_core(HmBf + r * 128, 384, HmBf + r * 128, 384, KBIG, sW1t, M, 128, m0, n0, As, Bs, acc);
    const int t = threadIdx.x;
    const int lane = t & 63, wave = t >> 6;
    const int wm = (wave >> 1) << 6, wn = (wave & 1) << 6;
    const int fr = lane & 15, quad = lane >> 4;
    float local = 0.f;
    #pragma unroll
    for (int ni = 0; ni < 4; ni++) {
        int gc = n0 + wn + ni * 16 + fr;
        float b = sb1[gc], w2 = sw2[gc];
        #pragma unroll
        for (int mi = 0; mi < 4; mi++) {
            #pragma unroll
            for (int reg = 0; reg < 4; reg++) {
                int gr = m0 + wm + mi * 16 + quad * 4 + reg;
                if (gr >= M) continue;
                local += fast_tanh(acc[mi][ni][reg] + b) * w2;
            }
        }
    }
    #pragma unroll
    for (int off = 1; off < 64; off <<= 1) local += __shfl_xor(local, off);
    if (lane == 0) red4[wave] = local;
    __syncthreads();
    if (t == 0)
        partial[(head * 3 + r) * MT_M + blockIdx.y] = red4[0] + red4[1] + red4[2] + red4[3];
}

__global__ void reduce12_kernel(const float* __restrict__ partial, float* __restrict__ scores)
{
    int z = blockIdx.x;
    int lane = threadIdx.x;   // 64 threads
    float s = 0.f;
    for (int i = lane; i < MT_M; i += 64) s += partial[z * MT_M + i];
    #pragma unroll
    for (int off = 1; off < 64; off <<= 1) s += __shfl_xor(s, off);
    if (lane == 0) scores[z] = s;
}

__global__ void compute_w_kernel(const float* __restrict__ scores, float* __restrict__ w, float invN)
{
    if (blockIdx.x == 0 && threadIdx.x == 0) {
        float wr[3] = {0.f, 0.f, 0.f};
        for (int h = 0; h < 4; h++) {
            float s0 = scores[h * 3 + 0] * invN;
            float s1 = scores[h * 3 + 1] * invN;
            float s2 = scores[h * 3 + 2] * invN;
            float mx = fmaxf(s0, fmaxf(s1, s2));
            float e0 = __expf(s0 - mx), e1 = __expf(s1 - mx), e2 = __expf(s2 - mx);
            float inv = 1.f / (e0 + e1 + e2);
            wr[0] += 0.25f * e0 * inv;
            wr[1] += 0.25f * e1 * inv;
            wr[2] += 0.25f * e2 * inv;
        }
        w[0] = wr[0]; w[1] = wr[1]; w[2] = wr[2];
    }
}

__global__ void mix_kernel(const float* __restrict__ Hm, const float* __restrict__ w,
                           float* __restrict__ h, short* __restrict__ hbf, int total4)
{
    int i = blockIdx.x * blockDim.x + threadIdx.x;
    if (i >= total4) return;
    int n = i >> 5, c4 = (i & 31) << 2;
    const float* row = Hm + (size_t)n * 384 + c4;
    float4 a = *(const float4*)row;
    float4 b = *(const float4*)(row + 128);
    float4 c = *(const float4*)(row + 256);
    float w0 = w[0], w1 = w[1], w2 = w[2];
    float4 v = make_float4(w0 * a.x + w1 * b.x + w2 * c.x,
                           w0 * a.y + w1 * b.y + w2 * c.y,
                           w0 * a.z + w1 * b.z + w2 * c.z,
                           w0 * a.w + w1 * b.w + w2 * c.w);
    *(float4*)(h + (size_t)n * 128 + c4) = v;
    unsigned p0 = ((unsigned)f2bf(v.y) << 16) | (unsigned)f2bf(v.x);
    unsigned p1 = ((unsigned)f2bf(v.w) << 16) | (unsigned)f2bf(v.z);
    *(uint2*)(hbf + (size_t)n * 128 + c4) = make_uint2(p0, p1);
}

// --------------------------- conversions -----------------------------------
__global__ void convert_bf16_kernel(const float* __restrict__ src, unsigned* __restrict__ dst, int n_pairs)
{
    int i = blockIdx.x * blockDim.x + threadIdx.x;
    if (i >= n_pairs) return;
    float2 f = ((const float2*)src)[i];
    dst[i] = ((unsigned)f2bf(f.y) << 16) | (unsigned)f2bf(f.x);
}

__global__ void prep_global_kernel(const float* __restrict__ lin1_W, const float* __restrict__ lin2_W,
                                   short* __restrict__ lin1Wt, short* __restrict__ lin2Wt)
{
    int id = blockIdx.x * blockDim.x + threadIdx.x;
    if (id < 98304) {
        int n = id / 768, k = id % 768;
        lin1Wt[id] = (short)f2bf(lin1_W[k * 128 + n]);
    } else if (id < 114688) {
        int r = id - 98304;
        int n = r / 128, k = r % 128;
        lin2Wt[r] = (short)f2bf(lin2_W[k * 128 + n]);
    }
}

// Combined per-layer prep: qkvsWt [4992][128] (q|k|v for 3 relations + Ws),
// gWt [128][256], sW1t [512][128], qkvsB [4992].
__global__ void prep_layer_kernel(
    const float* __restrict__ Wq, const float* __restrict__ Wk, const float* __restrict__ Wv,
    const float* __restrict__ Ws, const float* __restrict__ bq, const float* __restrict__ bk,
    const float* __restrict__ bv, const float* __restrict__ bs,
    const float* __restrict__ gW, const float* __restrict__ sW1,
    short* __restrict__ qkvsWt, short* __restrict__ gWt,
    short* __restrict__ sW1t, float* __restrict__ qkvsB)
{
    const int S0 = 638976;             // 4992*128
    const int S1 = S0 + 32768;         // + gW
    const int S2 = S1 + 65536;         // + sW1
    const int S3 = S2 + 4992;          // + bias
    int id = blockIdx.x * blockDim.x + threadIdx.x;
    if (id < S0) {
        int n = id / 128, k = id - n * 128;
        float v;
        if (n < 4608) {
            int r = n / 1536, j = n - r * 1536;
            if (j < 512)       v = Wq[(size_t)r * 65536 + k * 512 + j];
            else if (j < 1024) v = Wk[(size_t)r * 65536 + k * 512 + (j - 512)];
            else               v = Wv[(size_t)r * 65536 + k * 512 + (j - 1024)];
        } else {
            int m = n - 4608;
            int r = m / 128, c = m - r * 128;
            v = Ws[(size_t)r * 16384 + k * 128 + c];
        }
        qkvsWt[id] = (short)f2bf(v);
    } else if (id < S1) {
        int q = id - S0;
        int n = q / 256, k = q - n * 256;
        gWt[q] = (short)f2bf(gW[k * 128 + n]);
    } else if (id < S2) {
        int q = id - S1;
        int h = q / 16384, rem = q - h * 16384;
        int n = rem / 128, k = rem - n * 128;
        sW1t[q] = (short)f2bf(sW1[(size_t)h * 16384 + k * 128 + n]);
    } else if (id < S3) {
        int q = id - S2;
        float v;
        if (q < 4608) {
            int r = q / 1536, j = q - r * 1536;
            if (j < 512)       v = bq[r * 512 + j];
            else if (j < 1024) v = bk[r * 512 + (j - 512)];
            else               v = bv[r * 512 + (j - 1024)];
        } else {
            v = bs[q - 4608];
        }
        qkvsB[q] = v;
    }
}

// --------------------------- CSR build (once) ------------------------------
__global__ void zero_i32_kernel(int* __restrict__ p, int n)
{
    int i = blockIdx.x * blockDim.x + threadIdx.x;
    if (i < n) p[i] = 0;
}

__global__ void hist3_kernel(const int* __restrict__ edges, int* __restrict__ cnt3)
{
    int i = blockIdx.x * blockDim.x + threadIdx.x;
    if (i >= 3 * EE) return;
    int r = i / EE, e = i - r * EE;
    int d = edges[(size_t)r * 2 * EE + EE + e];
    atomicAdd(&cnt3[r * Nn + d], 1);
}

__global__ __launch_bounds__(1024) void scan3_kernel(const int* __restrict__ cnt3,
                                                     int* __restrict__ rowptr3)
{
    __shared__ int part[1024];
    const int r = blockIdx.x;
    const int* cnt = cnt3 + r * Nn;
    int* rowptr = rowptr3 + r * (Nn + 1);
    int tid = threadIdx.x;
    int per = (Nn + 1023) >> 10;
    int base = tid * per;
    int s = 0;
    for (int i = 0; i < per; i++) {
        int idx = base + i;
        if (idx < Nn) s += cnt[idx];
    }
    part[tid] = s;
    __syncthreads();
    for (int off = 1; off < 1024; off <<= 1) {
        int val = (tid >= off) ? part[tid - off] : 0;
        __syncthreads();
        part[tid] += val;
        __syncthreads();
    }
    int excl = (tid == 0) ? 0 : part[tid - 1];
    for (int i = 0; i < per; i++) {
        int idx = base + i;
        if (idx < Nn) { rowptr[idx] = excl; excl += cnt[idx]; }
    }
    if (tid == 1023) rowptr[Nn] = part[1023];
}

__global__ void scatter3_kernel(const int* __restrict__ edges,
                                const int* __restrict__ rowptr3, int* __restrict__ fill3,
                                int* __restrict__ col3)
{
    int i = blockIdx.x * blockDim.x + threadIdx.x;
    if (i >= 3 * EE) return;
    int r = i / EE, e = i - r * EE;
    int src = edges[(size_t)r * 2 * EE + e];
    int d   = edges[(size_t)r * 2 * EE + EE + e];
    int pos = rowptr3[r * (Nn + 1) + d] + atomicAdd(&fill3[r * Nn + d], 1);
    col3[r * EE + pos] = src;
}

// --------------------------- attention (all 3 relations) -------------------
// One wave per (dst,relation). qkv3: [3][N][1536]. U in/out: bf16 [N,384].
__global__ __launch_bounds__(256) void attn_kernel(
    const short* __restrict__ qkv3,
    const int* __restrict__ rowptr3, const int* __restrict__ col3,
    short* __restrict__ Ubf)
{
    int wid = ((blockIdx.x * blockDim.x + threadIdx.x) >> 6);
    int lane = threadIdx.x & 63;
    if (wid >= 3 * Nn) return;
    int r = wid / Nn, n = wid - r * Nn;
    const short* qkv = qkv3 + (size_t)r * Nn * 1536;
    const int* rowptr = rowptr3 + r * (Nn + 1);
    const int* colb = col3 + r * EE;
    int beg = rowptr[n], end = rowptr[n + 1];

    uint4 qv = ((const uint4*)(qkv + (size_t)n * 1536))[lane];
    float qf[8];
    unpack8(qv, qf);

    float m = -INFINITY, s = 0.f;
    float acc[8] = {0.f, 0.f, 0.f, 0.f, 0.f, 0.f, 0.f, 0.f};
    const float scale = 0.088388347648318447f; // 1/sqrt(128)

    for (int i = beg; i < end; i++) {
        int src = colb[i];
        const short* base = qkv + (size_t)src * 1536;
        uint4 kv4 = ((const uint4*)(base + 512))[lane];
        uint4 vv4 = ((const uint4*)(base + 1024))[lane];
        float kf[8];
        unpack8(kv4, kf);
        float p = qf[0] * kf[0] + qf[1] * kf[1] + qf[2] * kf[2] + qf[3] * kf[3]
                + qf[4] * kf[4] + qf[5] * kf[5] + qf[6] * kf[6] + qf[7] * kf[7];
        p += __shfl_xor(p, 1);
        p += __shfl_xor(p, 2);
        p += __shfl_xor(p, 4);
        p += __shfl_xor(p, 8);
        float l = p * scale;
        float nm = fmaxf(m, l);
        float sc = __expf(m - nm);
        float pe = __expf(l - nm);
        float vf[8];
        unpack8(vv4, vf);
        s = s * sc + pe;
        #pragma unroll
        for (int j = 0; j < 8; j++) acc[j] = acc[j] * sc + pe * vf[j];
        m = nm;
    }

    float inv = (s > 0.f) ? 1.f / s : 0.f;
    #pragma unroll
    for (int j = 0; j < 8; j++) acc[j] *= inv;
    #pragma unroll
    for (int j = 0; j < 8; j++) acc[j] += __shfl_xor(acc[j], 16);
    #pragma unroll
    for (int j = 0; j < 8; j++) acc[j] += __shfl_xor(acc[j], 32);

    if (lane < 16) {
        short* urow = Ubf + (size_t)n * 384 + r * 128 + lane * 8;
        uint4 old = *(uint4*)urow;
        float sv[8];
        unpack8(old, sv);
        #pragma unroll
        for (int j = 0; j < 8; j++) sv[j] += 0.25f * acc[j];
        unsigned p0 = ((unsigned)f2bf(sv[1]) << 16) | (unsigned)f2bf(sv[0]);
        unsigned p1 = ((unsigned)f2bf(sv[3]) << 16) | (unsigned)f2bf(sv[2]);
        unsigned p2 = ((unsigned)f2bf(sv[5]) << 16) | (unsigned)f2bf(sv[4]);
        unsigned p3 = ((unsigned)f2bf(sv[7]) << 16) | (unsigned)f2bf(sv[6]);
        *(uint4*)urow = make_uint4(p0, p1, p2, p3);
    }
}

// --------------------------- classifier -----------------------------------
__global__ void clf_kernel(const float* __restrict__ t, const float* __restrict__ W,
                           const float* __restrict__ b, float* __restrict__ out, int M)
{
    int n = blockIdx.x * blockDim.x + threadIdx.x;
    if (n >= M) return;
    const float* row = t + (size_t)n * 128;
    float a0 = b[0], a1 = b[1];
    #pragma unroll
    for (int kk = 0; kk < 128; kk++) {
        float a = row[kk];
        a0 += a * W[kk * 2];
        a1 += a * W[kk * 2 + 1];
    }
    out[n * 2] = a0;
    out[n * 2 + 1] = a1;
}

// ---------------------------------------------------------------------------
extern "C" void kernel_launch(void* const* d_in, const int* in_sizes, int n_in,
                              void* d_out, int out_size, void* d_ws, size_t ws_size,
                              hipStream_t stream)
{
    const float* x      = (const float*)d_in[0];
    const int*   edges  = (const int*)d_in[1];
    const float* lin1_W = (const float*)d_in[2];
    const float* lin1_b = (const float*)d_in[3];
    const int L0 = 4, L1 = 17;
    const float* lin2_W = (const float*)d_in[30];
    const float* lin2_b = (const float*)d_in[31];
    const float* clf_W  = (const float*)d_in[32];
    const float* clf_b  = (const float*)d_in[33];
    float* out = (float*)d_out;

    char* w = (char*)d_ws;
    size_t off = 0;
    auto alloc = [&](size_t bytes) { void* p = w + off; off = (off + bytes + 255) & ~(size_t)255; return p; };
    float* h      = (float*)alloc((size_t)Nn * 128 * 4);     // 15.4 MB
    short* h_bf   = (short*)alloc((size_t)Nn * 128 * 2);     //  7.7 MB
    short* U_bf   = (short*)alloc((size_t)Nn * 384 * 2);     // 23.0 MB
    // BIG union region (276.5 MB): qkv3 [3][N][1536] bf16  <->  x_bf [N,768] bf16
    //                              <->  Hm [N,384] f32 + Hm_bf [N,384] bf16
    char* BIG     = (char*)alloc((size_t)3 * Nn * 1536 * 2);
    short* qkv3   = (short*)BIG;
    short* x_bf   = (short*)BIG;
    float* Hm     = (float*)BIG;
    short* Hm_bf  = (short*)(BIG + (size_t)Nn * 384 * 4);
    float* lin2o  = (float*)BIG;                              // lin2 out (post layer-2)
    short* lin1Wt = (short*)alloc((size_t)98304 * 2);
    short* lin2Wt = (short*)alloc((size_t)16384 * 2);
    short* qkvsWt = (short*)alloc((size_t)2 * 638976 * 2);
    short* gWt    = (short*)alloc((size_t)2 * 32768 * 2);
    short* sW1t   = (short*)alloc((size_t)2 * 65536 * 2);
    float* qkvsB  = (float*)alloc((size_t)2 * 4992 * 4);
    int* rowptr3  = (int*)alloc((size_t)3 * (Nn + 1) * 4);
    int* cnt3     = (int*)alloc((size_t)3 * Nn * 4);
    int* col3     = (int*)alloc((size_t)3 * EE * 4);
    float* partial = (float*)alloc((size_t)12 * MT_M * 4);
    float* scores = (float*)alloc(12 * 4);
    float* wmix   = (float*)alloc(3 * 4);

    const int MT = MT_M;    // 235
    dim3 blk(256);

    // ---- prep ----
    {
        int n_pairs = Nn * 768 / 2;
        convert_bf16_kernel<<<(n_pairs + 255) / 256, blk, 0, stream>>>(x, (unsigned*)x_bf, n_pairs);
        prep_global_kernel<<<(114688 + 255) / 256, blk, 0, stream>>>(lin1_W, lin2_W, lin1Wt, lin2Wt);
        for (int l = 0; l < 2; l++) {
            int base = (l == 0) ? L0 : L1;
            prep_layer_kernel<<<(742272 + 255) / 256, blk, 0, stream>>>(
                (const float*)d_in[base + 0], (const float*)d_in[base + 2], (const float*)d_in[base + 4],
                (const float*)d_in[base + 6], (const float*)d_in[base + 1], (const float*)d_in[base + 3],
                (const float*)d_in[base + 5], (const float*)d_in[base + 7],
                (const float*)d_in[base + 8], (const float*)d_in[base + 10],
                qkvsWt + (size_t)l * 638976, gWt + (size_t)l * 32768,
                sW1t + (size_t)l * 65536, qkvsB + (size_t)l * 4992);
        }
        zero_i32_kernel<<<(3 * Nn + 255) / 256, blk, 0, stream>>>(cnt3, 3 * Nn);
        hist3_kernel<<<(3 * EE + 255) / 256, blk, 0, stream>>>(edges, cnt3);
        scan3_kernel<<<3, 1024, 0, stream>>>(cnt3, rowptr3);
        zero_i32_kernel<<<(3 * Nn + 255) / 256, blk, 0, stream>>>(cnt3, 3 * Nn);
        scatter3_kernel<<<(3 * EE + 255) / 256, blk, 0, stream>>>(edges, rowptr3, cnt3, col3);
    }

    // lin1: h = lrelu(x @ lin1_W + b)   (x_bf in BIG; done before qkv overwrites)
    gemm_mfma<<<dim3(1, MT), blk, 0, stream>>>(
        x_bf, 768, x_bf, 768, KBIG, lin1Wt, lin1_b, h, 128, h_bf, 128, Nn, 768, 1);

    for (int l = 0; l < 2; l++) {
        int base = (l == 0) ? L0 : L1;
        const float* gb  = (const float*)d_in[base + 9];
        const float* sb1 = (const float*)d_in[base + 11];
        const float* sw2 = (const float*)d_in[base + 12];
        short* lqkvsWt = qkvsWt + (size_t)l * 638976;
        short* lgWt    = gWt + (size_t)l * 32768;
        short* lsW1t   = sW1t + (size_t)l * 65536;
        float* lqkvsB  = qkvsB + (size_t)l * 4992;

        // fused q|k|v (3 relations) + Ws -> qkv3 + U_bf  (panel-resident GEMM)
        gemm_qkvs_v3<<<dim3(13, MT), blk, 0, stream>>>(
            h_bf, lqkvsWt, lqkvsB, qkv3, U_bf, Nn);

        // attention, all 3 relations: U += mean-head agg (in place, bf16)
        attn_kernel<<<(3 * Nn + 3) / 4, blk, 0, stream>>>(qkv3, rowptr3, col3, U_bf);

        // gate + combine (3 relations) -> Hm (fp32 + bf16)   [qkv3 dead now]
        gate_mfma<<<dim3(1, MT, 3), blk, 0, stream>>>(
            U_bf, h_bf, lgWt, gb, h, Hm, Hm_bf, Nn);

        // semantic attention
        semantic_mfma<<<dim3(4, MT, 3), blk, 0, stream>>>(Hm_bf, lsW1t, sb1, sw2, partial, Nn);
        reduce12_kernel<<<12, 64, 0, stream>>>(partial, scores);
        compute_w_kernel<<<1, 64, 0, stream>>>(scores, wmix, 1.f / (float)Nn);
        mix_kernel<<<(Nn * 32 + 255) / 256, blk, 0, stream>>>(Hm, wmix, h, h_bf, Nn * 32);
    }

    // lin2 + lrelu -> lin2o (BIG region, Hm dead after mix)
    gemm_mfma<<<dim3(1, MT), blk, 0, stream>>>(
        h_bf, 128, h_bf, 128, KBIG, lin2Wt, lin2_b, lin2o, 128, (short*)nullptr, 0, Nn, 128, 1);
    clf_kernel<<<(Nn + 255) / 256, blk, 0, stream>>>(lin2o, clf_W, clf_b, out, Nn);
}

// Round 3
// 907.454 us; speedup vs baseline: 1.1167x; 1.1111x over previous
//
#include <hip/hip_runtime.h>
#include <math.h>

#define Nn 30000
#define RR 3
#define EE 80000
#define MT_M 235      // ceil(Nn/128)

#define SAP 72        // padded LDS row stride (bf16 elems) for staged tiles
#define EP_LD 68      // per-wave epilogue scratch stride (floats)
#define KBIG 0x40000000

typedef __attribute__((ext_vector_type(8))) short bf16x8;
typedef __attribute__((ext_vector_type(4))) float f32x4;

__device__ __forceinline__ unsigned short f2bf(float f) {
    union { float f; unsigned u; } v; v.f = f;
    unsigned r = v.u + 0x7fff + ((v.u >> 16) & 1);
    return (unsigned short)(r >> 16);
}
__device__ __forceinline__ float fast_tanh(float x) {
    float e = __expf(2.f * x);
    return 1.f - 2.f / (e + 1.f);
}
__device__ __forceinline__ void unpack8(uint4 u, float* f) {
    union { unsigned u; float f; } a;
    a.u = u.x << 16;          f[0] = a.f;
    a.u = u.x & 0xffff0000u;  f[1] = a.f;
    a.u = u.y << 16;          f[2] = a.f;
    a.u = u.y & 0xffff0000u;  f[3] = a.f;
    a.u = u.z << 16;          f[4] = a.f;
    a.u = u.z & 0xffff0000u;  f[5] = a.f;
    a.u = u.w << 16;          f[6] = a.f;
    a.u = u.w & 0xffff0000u;  f[7] = a.f;
}

// ---------------------------------------------------------------------------
// LDS-staged MFMA GEMM core (128x128 tile, BK=64, 4 waves x 64x64).
// ---------------------------------------------------------------------------
__device__ __forceinline__ void mfma_core(
    const short* __restrict__ A, int lda,
    const short* __restrict__ A2, int lda2, int ksplit,
    const short* __restrict__ Bt,
    int M, int K, int m0, int n0,
    short* As, short* Bs, f32x4 (&acc)[4][4])
{
    const int t = threadIdx.x;
    const int srow = t >> 3;          // 0..31
    const int scol = (t & 7) << 3;    // 0..56 step 8
    const int lane = t & 63;
    const int wave = t >> 6;
    const int wm = (wave >> 1) << 6;
    const int wn = (wave & 1) << 6;
    const int fr = lane & 15;
    const int quad = lane >> 4;

    for (int k0 = 0; k0 < K; k0 += 64) {
        const short* Abase; int kk0, ldax;
        if (k0 < ksplit) { Abase = A;  kk0 = k0;          ldax = lda;  }
        else             { Abase = A2; kk0 = k0 - ksplit; ldax = lda2; }
        #pragma unroll
        for (int rr = 0; rr < 4; rr++) {
            int r = srow + rr * 32;
            int gr = m0 + r;
            bf16x8 va = {0, 0, 0, 0, 0, 0, 0, 0};
            if (gr < M) va = *(const bf16x8*)(Abase + (size_t)gr * ldax + kk0 + scol);
            *(bf16x8*)(As + r * SAP + scol) = va;
        }
        #pragma unroll
        for (int rr = 0; rr < 4; rr++) {
            int r = srow + rr * 32;
            bf16x8 vb = *(const bf16x8*)(Bt + (size_t)(n0 + r) * K + k0 + scol);
            *(bf16x8*)(Bs + r * SAP + scol) = vb;
        }
        __syncthreads();
        #pragma unroll
        for (int kc = 0; kc < 2; kc++) {
            bf16x8 af[4], bfr[4];
            #pragma unroll
            for (int i = 0; i < 4; i++)
                af[i] = *(const bf16x8*)(As + (wm + i * 16 + fr) * SAP + kc * 32 + quad * 8);
            #pragma unroll
            for (int i = 0; i < 4; i++)
                bfr[i] = *(const bf16x8*)(Bs + (wn + i * 16 + fr) * SAP + kc * 32 + quad * 8);
            #pragma unroll
            for (int mi = 0; mi < 4; mi++)
                #pragma unroll
                for (int ni = 0; ni < 4; ni++)
                    acc[mi][ni] = __builtin_amdgcn_mfma_f32_16x16x32_bf16(
                        af[mi], bfr[ni], acc[mi][ni], 0, 0, 0);
        }
        __syncthreads();
    }
}

// General GEMM: C = act(A @ Bt^T + bias). Wave-private LDS repack epilogue.
__global__ __launch_bounds__(256) void gemm_mfma(
    const short* __restrict__ A, int lda,
    const short* __restrict__ A2, int lda2, int ksplit,
    const short* __restrict__ Bt, const float* __restrict__ bias,
    float* __restrict__ C, int ldc, short* __restrict__ Cbf, int ldcbf,
    int M, int K, int act)
{
    __shared__ short As[128 * SAP];
    __shared__ short Bs[128 * SAP];
    f32x4 acc[4][4];
    #pragma unroll
    for (int i = 0; i < 4; i++)
        #pragma unroll
        for (int j = 0; j < 4; j++) acc[i][j] = (f32x4){0.f, 0.f, 0.f, 0.f};
    int m0 = blockIdx.y * 128, n0 = blockIdx.x * 128;
    mfma_core(A, lda, A2, lda2, ksplit, Bt, M, K, m0, n0, As, Bs, acc);

    const int t = threadIdx.x;
    const int lane = t & 63, wave = t >> 6;
    const int wm = (wave >> 1) << 6, wn = (wave & 1) << 6;
    const int fr = lane & 15, quad = lane >> 4;
    float* ws = (float*)As + wave * 16 * EP_LD;   // wave-private (post-barrier)
    const int rrow = lane >> 2;
    const int cseg = (lane & 3) << 4;
    #pragma unroll
    for (int mi = 0; mi < 4; mi++) {
        #pragma unroll
        for (int ni = 0; ni < 4; ni++)
            #pragma unroll
            for (int reg = 0; reg < 4; reg++)
                ws[(quad * 4 + reg) * EP_LD + ni * 16 + fr] = acc[mi][ni][reg];
        int gr = m0 + wm + mi * 16 + rrow;
        if (gr >= M) continue;
        int gc = n0 + wn + cseg;
        float vals[16];
        #pragma unroll
        for (int j = 0; j < 16; j++) {
            float v = ws[rrow * EP_LD + cseg + j] + bias[gc + j];
            if (act == 1) v = (v >= 0.f) ? v : 0.01f * v;
            vals[j] = v;
        }
        if (C) {
            float* cp = C + (size_t)gr * ldc + gc;
            #pragma unroll
            for (int j4 = 0; j4 < 4; j4++)
                *(float4*)(cp + j4 * 4) = make_float4(vals[j4 * 4], vals[j4 * 4 + 1],
                                                      vals[j4 * 4 + 2], vals[j4 * 4 + 3]);
        }
        if (Cbf) {
            unsigned pk[8];
            #pragma unroll
            for (int j2 = 0; j2 < 8; j2++)
                pk[j2] = ((unsigned)f2bf(vals[2 * j2 + 1]) << 16) | (unsigned)f2bf(vals[2 * j2]);
            unsigned* bp = (unsigned*)(Cbf + (size_t)gr * ldcbf + gc);
            *(uint4*)bp       = make_uint4(pk[0], pk[1], pk[2], pk[3]);
            *(uint4*)(bp + 4) = make_uint4(pk[4], pk[5], pk[6], pk[7]);
        }
    }
}

// ---------------------------------------------------------------------------
// v4 fused projection: qhat (= h@G + c, scaled, 3 rel x 512) | U-init (h@Ws+bs).
// Wt4: [1920][128]; bias4 [1920].
//   bx<12: -> qhat3[r=bx/4][gr][(bx%4)*128+..]
//   bx>=12: -> Ubf[gr*384 + (bx-12)*128 + ..]
// ---------------------------------------------------------------------------
__global__ __launch_bounds__(256) void gemm_qkvs_v4(
    const short* __restrict__ A,       // h_bf [N,128]
    const short* __restrict__ Wt, const float* __restrict__ bias,
    short* __restrict__ qhat3, short* __restrict__ Ubf, int M)
{
    __shared__ short As[128 * SAP];
    __shared__ short Bs[128 * SAP];
    f32x4 acc[4][4];
    #pragma unroll
    for (int i = 0; i < 4; i++)
        #pragma unroll
        for (int j = 0; j < 4; j++) acc[i][j] = (f32x4){0.f, 0.f, 0.f, 0.f};
    int m0 = blockIdx.y * 128, bx = blockIdx.x, n0 = bx * 128;
    mfma_core(A, 128, A, 128, KBIG, Wt, M, 128, m0, n0, As, Bs, acc);

    const int t = threadIdx.x;
    const int lane = t & 63, wave = t >> 6;
    const int wm = (wave >> 1) << 6, wn = (wave & 1) << 6;
    const int fr = lane & 15, quad = lane >> 4;
    float* ws = (float*)As + wave * 16 * EP_LD;
    const int rrow = lane >> 2;
    const int cseg = (lane & 3) << 4;
    #pragma unroll
    for (int mi = 0; mi < 4; mi++) {
        #pragma unroll
        for (int ni = 0; ni < 4; ni++)
            #pragma unroll
            for (int reg = 0; reg < 4; reg++)
                ws[(quad * 4 + reg) * EP_LD + ni * 16 + fr] = acc[mi][ni][reg];
        int gr = m0 + wm + mi * 16 + rrow;
        if (gr >= M) continue;
        int lc = wn + cseg;               // 0..112 local col start
        float vals[16];
        #pragma unroll
        for (int j = 0; j < 16; j++)
            vals[j] = ws[rrow * EP_LD + cseg + j] + bias[n0 + lc + j];
        unsigned pk[8];
        #pragma unroll
        for (int j2 = 0; j2 < 8; j2++)
            pk[j2] = ((unsigned)f2bf(vals[2 * j2 + 1]) << 16) | (unsigned)f2bf(vals[2 * j2]);
        short* dst;
        if (bx < 12) {
            int r = bx >> 2;
            dst = qhat3 + ((size_t)(r * Nn + gr)) * 512 + (bx - r * 4) * 128 + lc;
        } else {
            dst = Ubf + (size_t)gr * 384 + (bx - 12) * 128 + lc;
        }
        unsigned* bp = (unsigned*)dst;
        *(uint4*)bp       = make_uint4(pk[0], pk[1], pk[2], pk[3]);
        *(uint4*)(bp + 4) = make_uint4(pk[4], pk[5], pk[6], pk[7]);
    }
}

// ---------------------------------------------------------------------------
// v4 attention: per (dst,rel) wave. logit[h] = qhat[dst,h*128:].h[src] (scale
// folded into qhat). Online softmax per 16-lane head group; accumulate
// Ah[h][128] = sum alpha*h[src]. Writes Ah3 [3][N][512] bf16.
// Gather = 256 B/edge from h_bf (7.7 MB, L2-resident).
// ---------------------------------------------------------------------------
__global__ __launch_bounds__(256) void attn_v4(
    const short* __restrict__ qhat3, const short* __restrict__ hbf,
    const int* __restrict__ rowptr3, const int* __restrict__ col3,
    short* __restrict__ Ah3)
{
    int wid = ((blockIdx.x * blockDim.x + threadIdx.x) >> 6);
    int lane = threadIdx.x & 63;
    if (wid >= 3 * Nn) return;
    int r = wid / Nn, n = wid - r * Nn;
    const int* rowptr = rowptr3 + r * (Nn + 1);
    const int* colb = col3 + r * EE;
    int beg = rowptr[n], end = rowptr[n + 1];

    uint4 qv = ((const uint4*)(qhat3 + ((size_t)r * Nn + n) * 512))[lane];
    float qf[8];
    unpack8(qv, qf);
    const int l16 = lane & 15;

    float m = -INFINITY, s = 0.f;
    float acc[8] = {0.f, 0.f, 0.f, 0.f, 0.f, 0.f, 0.f, 0.f};

    for (int i = beg; i < end; i++) {
        int src = colb[i];
        uint4 hv = ((const uint4*)(hbf + (size_t)src * 128))[l16];
        float hf[8];
        unpack8(hv, hf);
        float p = qf[0] * hf[0] + qf[1] * hf[1] + qf[2] * hf[2] + qf[3] * hf[3]
                + qf[4] * hf[4] + qf[5] * hf[5] + qf[6] * hf[6] + qf[7] * hf[7];
        p += __shfl_xor(p, 1);
        p += __shfl_xor(p, 2);
        p += __shfl_xor(p, 4);
        p += __shfl_xor(p, 8);
        float nm = fmaxf(m, p);
        float sc = __expf(m - nm);
        float pe = __expf(p - nm);
        s = s * sc + pe;
        #pragma unroll
        for (int j = 0; j < 8; j++) acc[j] = acc[j] * sc + pe * hf[j];
        m = nm;
    }

    float inv = (s > 0.f) ? 1.f / s : 0.f;
    #pragma unroll
    for (int j = 0; j < 8; j++) acc[j] *= inv;

    unsigned p0 = ((unsigned)f2bf(acc[1]) << 16) | (unsigned)f2bf(acc[0]);
    unsigned p1 = ((unsigned)f2bf(acc[3]) << 16) | (unsigned)f2bf(acc[2]);
    unsigned p2 = ((unsigned)f2bf(acc[5]) << 16) | (unsigned)f2bf(acc[4]);
    unsigned p3 = ((unsigned)f2bf(acc[7]) << 16) | (unsigned)f2bf(acc[6]);
    *(uint4*)(Ah3 + ((size_t)r * Nn + n) * 512 + lane * 8) = make_uint4(p0, p1, p2, p3);
}

// ---------------------------------------------------------------------------
// v4 U finalize: U_bf += Ah @ Wvs^T (1/4 folded) + mask*bvmean.  K=512.
// mask (edges exist) read from rowptr3. In-place on U_bf.
// ---------------------------------------------------------------------------
__global__ __launch_bounds__(256) void ufin_mfma(
    const short* __restrict__ Ah3, const short* __restrict__ wvst,
    const float* __restrict__ bvmean, const int* __restrict__ rowptr3,
    short* __restrict__ U_bf, int M)
{
    __shared__ short As[128 * SAP];
    __shared__ short Bs[128 * SAP];
    f32x4 acc[4][4];
    #pragma unroll
    for (int i = 0; i < 4; i++)
        #pragma unroll
        for (int j = 0; j < 4; j++) acc[i][j] = (f32x4){0.f, 0.f, 0.f, 0.f};
    int r = blockIdx.z;
    int m0 = blockIdx.y * 128;
    const short* Ar = Ah3 + (size_t)r * Nn * 512;
    mfma_core(Ar, 512, Ar, 512, KBIG, wvst + r * 65536, M, 512, m0, 0, As, Bs, acc);

    const int t = threadIdx.x;
    const int lane = t & 63, wave = t >> 6;
    const int wm = (wave >> 1) << 6, wn = (wave & 1) << 6;
    const int fr = lane & 15, quad = lane >> 4;
    float* ws = (float*)As + wave * 16 * EP_LD;
    const int rrow = lane >> 2;
    const int cseg = (lane & 3) << 4;
    #pragma unroll
    for (int mi = 0; mi < 4; mi++) {
        #pragma unroll
        for (int ni = 0; ni < 4; ni++)
            #pragma unroll
            for (int reg = 0; reg < 4; reg++)
                ws[(quad * 4 + reg) * EP_LD + ni * 16 + fr] = acc[mi][ni][reg];
        int gr = m0 + wm + mi * 16 + rrow;
        if (gr >= M) continue;
        int gc = wn + cseg;
        int be = rowptr3[r * (Nn + 1) + gr];
        int en = rowptr3[r * (Nn + 1) + gr + 1];
        float mk = (en > be) ? 1.f : 0.f;
        short* up = U_bf + (size_t)gr * 384 + r * 128 + gc;
        uint4 u0 = *(const uint4*)up;
        uint4 u1 = *(const uint4*)(up + 8);
        float uv[16];
        unpack8(u0, uv); unpack8(u1, uv + 8);
        float vals[16];
        #pragma unroll
        for (int j = 0; j < 16; j++)
            vals[j] = ws[rrow * EP_LD + cseg + j] + uv[j] + mk * bvmean[r * 128 + gc + j];
        unsigned pk[8];
        #pragma unroll
        for (int j2 = 0; j2 < 8; j2++)
            pk[j2] = ((unsigned)f2bf(vals[2 * j2 + 1]) << 16) | (unsigned)f2bf(vals[2 * j2]);
        unsigned* bp = (unsigned*)up;
        *(uint4*)bp       = make_uint4(pk[0], pk[1], pk[2], pk[3]);
        *(uint4*)(bp + 4) = make_uint4(pk[4], pk[5], pk[6], pk[7]);
    }
}

// Gate (z = relation): Z = sigmoid([U_r|h] @ gW + gb); Hm_r = tanh(U_r)*Z + h*(1-Z).
__global__ __launch_bounds__(256) void gate_mfma(
    const short* __restrict__ Ubf,   // [N,384] bf16
    const short* __restrict__ Hbf,   // [N,128] bf16
    const short* __restrict__ gWt, const float* __restrict__ gb,
    const float* __restrict__ Hf,    // [N,128] fp32
    float* __restrict__ Hm, short* __restrict__ HmBf,   // [N,384]
    int M)
{
    __shared__ short As[128 * SAP];
    __shared__ short Bs[128 * SAP];
    f32x4 acc[4][4];
    #pragma unroll
    for (int i = 0; i < 4; i++)
        #pragma unroll
        for (int j = 0; j < 4; j++) acc[i][j] = (f32x4){0.f, 0.f, 0.f, 0.f};
    int r = blockIdx.z;
    int m0 = blockIdx.y * 128;
    mfma_core(Ubf + r * 128, 384, Hbf, 128, 128, gWt, M, 256, m0, 0, As, Bs, acc);

    const int t = threadIdx.x;
    const int lane = t & 63, wave = t >> 6;
    const int wm = (wave >> 1) << 6, wn = (wave & 1) << 6;
    const int fr = lane & 15, quad = lane >> 4;
    float* ws = (float*)As + wave * 16 * EP_LD;
    const int rrow = lane >> 2;
    const int cseg = (lane & 3) << 4;
    #pragma unroll
    for (int mi = 0; mi < 4; mi++) {
        #pragma unroll
        for (int ni = 0; ni < 4; ni++)
            #pragma unroll
            for (int reg = 0; reg < 4; reg++)
                ws[(quad * 4 + reg) * EP_LD + ni * 16 + fr] = acc[mi][ni][reg];
        int gr = m0 + wm + mi * 16 + rrow;
        if (gr >= M) continue;
        int gc = wn + cseg;
        const short* up = Ubf + (size_t)gr * 384 + r * 128 + gc;
        const float* hp = Hf + (size_t)gr * 128 + gc;
        float uv[16], hv[16];
        uint4 u0 = *(const uint4*)up;
        uint4 u1 = *(const uint4*)(up + 8);
        unpack8(u0, uv); unpack8(u1, uv + 8);
        #pragma unroll
        for (int j4 = 0; j4 < 4; j4++)
            *(float4*)(hv + j4 * 4) = *(const float4*)(hp + j4 * 4);
        float vals[16];
        #pragma unroll
        for (int j = 0; j < 16; j++) {
            float g = ws[rrow * EP_LD + cseg + j] + gb[gc + j];
            float z = 1.f / (1.f + __expf(-g));
            vals[j] = fast_tanh(uv[j]) * z + hv[j] * (1.f - z);
        }
        float* cp = Hm + (size_t)gr * 384 + r * 128 + gc;
        #pragma unroll
        for (int j4 = 0; j4 < 4; j4++)
            *(float4*)(cp + j4 * 4) = make_float4(vals[j4 * 4], vals[j4 * 4 + 1],
                                                  vals[j4 * 4 + 2], vals[j4 * 4 + 3]);
        unsigned pk[8];
        #pragma unroll
        for (int j2 = 0; j2 < 8; j2++)
            pk[j2] = ((unsigned)f2bf(vals[2 * j2 + 1]) << 16) | (unsigned)f2bf(vals[2 * j2]);
        unsigned* bp = (unsigned*)(HmBf + (size_t)gr * 384 + r * 128 + gc);
        *(uint4*)bp       = make_uint4(pk[0], pk[1], pk[2], pk[3]);
        *(uint4*)(bp + 4) = make_uint4(pk[4], pk[5], pk[6], pk[7]);
    }
}

// Semantic partial sums (no atomics).
__global__ __launch_bounds__(256) void semantic_mfma(
    const short* __restrict__ HmBf, const short* __restrict__ sW1t,
    const float* __restrict__ sb1, const float* __restrict__ sw2,
    float* __restrict__ partial, int M)
{
    __shared__ short As[128 * SAP];
    __shared__ short Bs[128 * SAP];
    __shared__ float red4[4];
    f32x4 acc[4][4];
    #pragma unroll
    for (int i = 0; i < 4; i++)
        #pragma unroll
        for (int j = 0; j < 4; j++) acc[i][j] = (f32x4){0.f, 0.f, 0.f, 0.f};
    int head = blockIdx.x, r = blockIdx.z;
    int m0 = blockIdx.y * 128, n0 = head * 128;
    mfma_core(HmBf + r * 128, 384, HmBf + r * 128, 384, KBIG, sW1t, M, 128, m0, n0, As, Bs, acc);
    const int t = threadIdx.x;
    const int lane = t & 63, wave = t >> 6;
    const int wm = (wave >> 1) << 6, wn = (wave & 1) << 6;
    const int fr = lane & 15, quad = lane >> 4;
    float local = 0.f;
    #pragma unroll
    for (int ni = 0; ni < 4; ni++) {
        int gc = n0 + wn + ni * 16 + fr;
        float b = sb1[gc], w2 = sw2[gc];
        #pragma unroll
        for (int mi = 0; mi < 4; mi++) {
            #pragma unroll
            for (int reg = 0; reg < 4; reg++) {
                int gr = m0 + wm + mi * 16 + quad * 4 + reg;
                if (gr >= M) continue;
                local += fast_tanh(acc[mi][ni][reg] + b) * w2;
            }
        }
    }
    #pragma unroll
    for (int off = 1; off < 64; off <<= 1) local += __shfl_xor(local, off);
    if (lane == 0) red4[wave] = local;
    __syncthreads();
    if (t == 0)
        partial[(head * 3 + r) * MT_M + blockIdx.y] = red4[0] + red4[1] + red4[2] + red4[3];
}

__global__ void reduce12_kernel(const float* __restrict__ partial, float* __restrict__ scores)
{
    int z = blockIdx.x;
    int lane = threadIdx.x;   // 64 threads
    float s = 0.f;
    for (int i = lane; i < MT_M; i += 64) s += partial[z * MT_M + i];
    #pragma unroll
    for (int off = 1; off < 64; off <<= 1) s += __shfl_xor(s, off);
    if (lane == 0) scores[z] = s;
}

__global__ void compute_w_kernel(const float* __restrict__ scores, float* __restrict__ w, float invN)
{
    if (blockIdx.x == 0 && threadIdx.x == 0) {
        float wr[3] = {0.f, 0.f, 0.f};
        for (int h = 0; h < 4; h++) {
            float s0 = scores[h * 3 + 0] * invN;
            float s1 = scores[h * 3 + 1] * invN;
            float s2 = scores[h * 3 + 2] * invN;
            float mx = fmaxf(s0, fmaxf(s1, s2));
            float e0 = __expf(s0 - mx), e1 = __expf(s1 - mx), e2 = __expf(s2 - mx);
            float inv = 1.f / (e0 + e1 + e2);
            wr[0] += 0.25f * e0 * inv;
            wr[1] += 0.25f * e1 * inv;
            wr[2] += 0.25f * e2 * inv;
        }
        w[0] = wr[0]; w[1] = wr[1]; w[2] = wr[2];
    }
}

__global__ void mix_kernel(const float* __restrict__ Hm, const float* __restrict__ w,
                           float* __restrict__ h, short* __restrict__ hbf, int total4)
{
    int i = blockIdx.x * blockDim.x + threadIdx.x;
    if (i >= total4) return;
    int n = i >> 5, c4 = (i & 31) << 2;
    const float* row = Hm + (size_t)n * 384 + c4;
    float4 a = *(const float4*)row;
    float4 b = *(const float4*)(row + 128);
    float4 c = *(const float4*)(row + 256);
    float w0 = w[0], w1 = w[1], w2 = w[2];
    float4 v = make_float4(w0 * a.x + w1 * b.x + w2 * c.x,
                           w0 * a.y + w1 * b.y + w2 * c.y,
                           w0 * a.z + w1 * b.z + w2 * c.z,
                           w0 * a.w + w1 * b.w + w2 * c.w);
    *(float4*)(h + (size_t)n * 128 + c4) = v;
    unsigned p0 = ((unsigned)f2bf(v.y) << 16) | (unsigned)f2bf(v.x);
    unsigned p1 = ((unsigned)f2bf(v.w) << 16) | (unsigned)f2bf(v.z);
    *(uint2*)(hbf + (size_t)n * 128 + c4) = make_uint2(p0, p1);
}

// --------------------------- conversions -----------------------------------
__global__ void convert_bf16_kernel(const float* __restrict__ src, unsigned* __restrict__ dst, int n_pairs)
{
    int i = blockIdx.x * blockDim.x + threadIdx.x;
    if (i >= n_pairs) return;
    float2 f = ((const float2*)src)[i];
    dst[i] = ((unsigned)f2bf(f.y) << 16) | (unsigned)f2bf(f.x);
}

__global__ void prep_global_kernel(const float* __restrict__ lin1_W, const float* __restrict__ lin2_W,
                                   short* __restrict__ lin1Wt, short* __restrict__ lin2Wt)
{
    int id = blockIdx.x * blockDim.x + threadIdx.x;
    if (id < 98304) {
        int n = id / 768, k = id % 768;
        lin1Wt[id] = (short)f2bf(lin1_W[k * 128 + n]);
    } else if (id < 114688) {
        int r = id - 98304;
        int n = r / 128, k = r % 128;
        lin2Wt[r] = (short)f2bf(lin2_W[k * 128 + n]);
    }
}

// v4 per-layer prep (everything except G): Ws rows of Wt4, gWt, sW1t, wvst,
// bs bias, bvmean.  wvst[r][d][h*128+j] = Wv[r][j][h*128+d] / 4.
__global__ void prep_layer_v4(
    const float* __restrict__ Ws, const float* __restrict__ bs,
    const float* __restrict__ gW, const float* __restrict__ sW1,
    const float* __restrict__ Wv, const float* __restrict__ bv,
    short* __restrict__ Wt4, short* __restrict__ gWt,
    short* __restrict__ sW1t, short* __restrict__ wvst,
    float* __restrict__ B4, float* __restrict__ bvmean)
{
    const int S0 = 49152;              // Ws rows (384*128)
    const int S1 = S0 + 32768;         // gWt
    const int S2 = S1 + 65536;         // sW1t
    const int S3 = S2 + 196608;        // wvst [3][128][512]
    const int S4 = S3 + 384;           // bs
    const int S5 = S4 + 384;           // bvmean
    int id = blockIdx.x * blockDim.x + threadIdx.x;
    if (id < S0) {
        int n = id / 128, k = id - n * 128;
        int r = n >> 7, c = n & 127;
        Wt4[(size_t)(1536 + n) * 128 + k] = (short)f2bf(Ws[(size_t)r * 16384 + k * 128 + c]);
    } else if (id < S1) {
        int q = id - S0;
        int n = q / 256, k = q - n * 256;
        gWt[q] = (short)f2bf(gW[k * 128 + n]);
    } else if (id < S2) {
        int q = id - S1;
        int h = q / 16384, rem = q - h * 16384;
        int n = rem / 128, k = rem - n * 128;
        sW1t[q] = (short)f2bf(sW1[(size_t)h * 16384 + k * 128 + n]);
    } else if (id < S3) {
        int q = id - S2;
        int r = q / 65536, rem = q - r * 65536;
        int d = rem / 512, mcol = rem - d * 512;
        int hh = mcol >> 7, j = mcol & 127;
        wvst[q] = (short)f2bf(0.25f * Wv[(size_t)r * 65536 + j * 512 + hh * 128 + d]);
    } else if (id < S4) {
        int q = id - S3;
        B4[1536 + q] = bs[q];
    } else if (id < S5) {
        int q = id - S4;           // r*128 + d
        int r = q >> 7, d = q & 127;
        bvmean[q] = 0.25f * (bv[r * 512 + d] + bv[r * 512 + 128 + d]
                           + bv[r * 512 + 256 + d] + bv[r * 512 + 384 + d]);
    }
}

// G precompute: block (h, r, layer). G = Wq_h @ Wk_h^T, scaled by 1/sqrt(DH).
// Writes Bt rows r*512+h*128+j of Wt4 (col i) and bias c[j] = scale*(Wk_h@bq_h).
__global__ __launch_bounds__(256) void gmat_kernel(
    const float* __restrict__ Wq0, const float* __restrict__ Wk0, const float* __restrict__ bq0,
    const float* __restrict__ Wq1, const float* __restrict__ Wk1, const float* __restrict__ bq1,
    short* __restrict__ Wt4, float* __restrict__ B4)
{
    __shared__ float WqL[128 * 128];   // stored transposed: [d][i]
    __shared__ float WkL[128 * 128];   // stored [j][d]
    int h = blockIdx.x, r = blockIdx.y, l = blockIdx.z;
    const float* Wq = l ? Wq1 : Wq0;
    const float* Wk = l ? Wk1 : Wk0;
    const float* bq = l ? bq1 : bq0;
    short* Wt = Wt4 + (size_t)l * 245760;
    float* Bb = B4 + l * 1920;
    const float scale = 0.088388347648318447f;   // 1/sqrt(128)
    int t = threadIdx.x;
    for (int idx = t; idx < 16384; idx += 256) {
        int a = idx >> 7, b = idx & 127;
        // WqL[d][i] = Wq[i, h*128+d]  (a=d, b=i): scattered read, tiny kernel
        WqL[idx] = Wq[(size_t)r * 65536 + b * 512 + h * 128 + a];
        // WkL[j][d] = Wk[j, h*128+d]  (a=j, b=d): row-ish read
        WkL[idx] = Wk[(size_t)r * 65536 + a * 512 + h * 128 + b];
    }
    __syncthreads();
    for (int out = t; out < 16384; out += 256) {
        int i = out & 127, j = out >> 7;       // i per-lane (coalesced write), j wave-uniform
        float dot = 0.f;
        #pragma unroll 8
        for (int d = 0; d < 128; d++)
            dot += WqL[d * 128 + i] * WkL[j * 128 + d];
        Wt[(size_t)(r * 512 + h * 128 + j) * 128 + i] = (short)f2bf(scale * dot);
    }
    if (t < 128) {
        const float* bqh = bq + r * 512 + h * 128;
        float c = 0.f;
        for (int d = 0; d < 128; d++) c += bqh[d] * WkL[t * 128 + d];
        Bb[r * 512 + h * 128 + t] = scale * c;
    }
}

// --------------------------- CSR build (once) ------------------------------
__global__ void zero_i32_kernel(int* __restrict__ p, int n)
{
    int i = blockIdx.x * blockDim.x + threadIdx.x;
    if (i < n) p[i] = 0;
}

__global__ void hist3_kernel(const int* __restrict__ edges, int* __restrict__ cnt3)
{
    int i = blockIdx.x * blockDim.x + threadIdx.x;
    if (i >= 3 * EE) return;
    int r = i / EE, e = i - r * EE;
    int d = edges[(size_t)r * 2 * EE + EE + e];
    atomicAdd(&cnt3[r * Nn + d], 1);
}

__global__ __launch_bounds__(1024) void scan3_kernel(const int* __restrict__ cnt3,
                                                     int* __restrict__ rowptr3)
{
    __shared__ int part[1024];
    const int r = blockIdx.x;
    const int* cnt = cnt3 + r * Nn;
    int* rowptr = rowptr3 + r * (Nn + 1);
    int tid = threadIdx.x;
    int per = (Nn + 1023) >> 10;
    int base = tid * per;
    int s = 0;
    for (int i = 0; i < per; i++) {
        int idx = base + i;
        if (idx < Nn) s += cnt[idx];
    }
    part[tid] = s;
    __syncthreads();
    for (int off = 1; off < 1024; off <<= 1) {
        int val = (tid >= off) ? part[tid - off] : 0;
        __syncthreads();
        part[tid] += val;
        __syncthreads();
    }
    int excl = (tid == 0) ? 0 : part[tid - 1];
    for (int i = 0; i < per; i++) {
        int idx = base + i;
        if (idx < Nn) { rowptr[idx] = excl; excl += cnt[idx]; }
    }
    if (tid == 1023) rowptr[Nn] = part[1023];
}

__global__ void scatter3_kernel(const int* __restrict__ edges,
                                const int* __restrict__ rowptr3, int* __restrict__ fill3,
                                int* __restrict__ col3)
{
    int i = blockIdx.x * blockDim.x + threadIdx.x;
    if (i >= 3 * EE) return;
    int r = i / EE, e = i - r * EE;
    int src = edges[(size_t)r * 2 * EE + e];
    int d   = edges[(size_t)r * 2 * EE + EE + e];
    int pos = rowptr3[r * (Nn + 1) + d] + atomicAdd(&fill3[r * Nn + d], 1);
    col3[r * EE + pos] = src;
}

// --------------------------- classifier -----------------------------------
__global__ void clf_kernel(const float* __restrict__ t, const float* __restrict__ W,
                           const float* __restrict__ b, float* __restrict__ out, int M)
{
    int n = blockIdx.x * blockDim.x + threadIdx.x;
    if (n >= M) return;
    const float* row = t + (size_t)n * 128;
    float a0 = b[0], a1 = b[1];
    #pragma unroll
    for (int kk = 0; kk < 128; kk++) {
        float a = row[kk];
        a0 += a * W[kk * 2];
        a1 += a * W[kk * 2 + 1];
    }
    out[n * 2] = a0;
    out[n * 2 + 1] = a1;
}

// ---------------------------------------------------------------------------
extern "C" void kernel_launch(void* const* d_in, const int* in_sizes, int n_in,
                              void* d_out, int out_size, void* d_ws, size_t ws_size,
                              hipStream_t stream)
{
    const float* x      = (const float*)d_in[0];
    const int*   edges  = (const int*)d_in[1];
    const float* lin1_W = (const float*)d_in[2];
    const float* lin1_b = (const float*)d_in[3];
    const int L0 = 4, L1 = 17;
    const float* lin2_W = (const float*)d_in[30];
    const float* lin2_b = (const float*)d_in[31];
    const float* clf_W  = (const float*)d_in[32];
    const float* clf_b  = (const float*)d_in[33];
    float* out = (float*)d_out;

    char* w = (char*)d_ws;
    size_t off = 0;
    auto alloc = [&](size_t bytes) { void* p = w + off; off = (off + bytes + 255) & ~(size_t)255; return p; };
    float* h      = (float*)alloc((size_t)Nn * 128 * 4);     // 15.4 MB
    short* h_bf   = (short*)alloc((size_t)Nn * 128 * 2);     //  7.7 MB
    short* U_bf   = (short*)alloc((size_t)Nn * 384 * 2);     // 23.0 MB
    // BIG union (184.3 MB): qhat3 [3][N][512] + Ah3 [3][N][512] bf16
    //   <-> x_bf [N,768] bf16  <-> Hm [N,384] f32 + Hm_bf [N,384] bf16 <-> lin2o
    const size_t QH = (size_t)3 * Nn * 512 * 2;
    char* BIG     = (char*)alloc(2 * QH);
    short* qhat3  = (short*)BIG;
    short* Ah3    = (short*)(BIG + QH);
    short* x_bf   = (short*)BIG;
    float* Hm     = (float*)BIG;
    short* Hm_bf  = (short*)(BIG + (size_t)Nn * 384 * 4);
    float* lin2o  = (float*)BIG;
    short* lin1Wt = (short*)alloc((size_t)98304 * 2);
    short* lin2Wt = (short*)alloc((size_t)16384 * 2);
    short* qkvsWt4 = (short*)alloc((size_t)2 * 245760 * 2);  // [layer][1920][128]
    short* gWt    = (short*)alloc((size_t)2 * 32768 * 2);
    short* sW1t   = (short*)alloc((size_t)2 * 65536 * 2);
    short* wvst   = (short*)alloc((size_t)2 * 196608 * 2);   // [layer][3][128][512]
    float* qkvsB4 = (float*)alloc((size_t)2 * 1920 * 4);
    float* bvmean = (float*)alloc((size_t)2 * 384 * 4);
    int* rowptr3  = (int*)alloc((size_t)3 * (Nn + 1) * 4);
    int* cnt3     = (int*)alloc((size_t)3 * Nn * 4);
    int* col3     = (int*)alloc((size_t)3 * EE * 4);
    float* partial = (float*)alloc((size_t)12 * MT_M * 4);
    float* scores = (float*)alloc(12 * 4);
    float* wmix   = (float*)alloc(3 * 4);

    const int MT = MT_M;    // 235
    dim3 blk(256);

    // ---- prep ----
    {
        int n_pairs = Nn * 768 / 2;
        convert_bf16_kernel<<<(n_pairs + 255) / 256, blk, 0, stream>>>(x, (unsigned*)x_bf, n_pairs);
        prep_global_kernel<<<(114688 + 255) / 256, blk, 0, stream>>>(lin1_W, lin2_W, lin1Wt, lin2Wt);
        for (int l = 0; l < 2; l++) {
            int base = (l == 0) ? L0 : L1;
            prep_layer_v4<<<(344832 + 255) / 256, blk, 0, stream>>>(
                (const float*)d_in[base + 6], (const float*)d_in[base + 7],
                (const float*)d_in[base + 8], (const float*)d_in[base + 10],
                (const float*)d_in[base + 4], (const float*)d_in[base + 5],
                qkvsWt4 + (size_t)l * 245760, gWt + (size_t)l * 32768,
                sW1t + (size_t)l * 65536, wvst + (size_t)l * 196608,
                qkvsB4 + (size_t)l * 1920, bvmean + (size_t)l * 384);
        }
        gmat_kernel<<<dim3(4, 3, 2), blk, 0, stream>>>(
            (const float*)d_in[L0 + 0], (const float*)d_in[L0 + 2], (const float*)d_in[L0 + 1],
            (const float*)d_in[L1 + 0], (const float*)d_in[L1 + 2], (const float*)d_in[L1 + 1],
            qkvsWt4, qkvsB4);
        zero_i32_kernel<<<(3 * Nn + 255) / 256, blk, 0, stream>>>(cnt3, 3 * Nn);
        hist3_kernel<<<(3 * EE + 255) / 256, blk, 0, stream>>>(edges, cnt3);
        scan3_kernel<<<3, 1024, 0, stream>>>(cnt3, rowptr3);
        zero_i32_kernel<<<(3 * Nn + 255) / 256, blk, 0, stream>>>(cnt3, 3 * Nn);
        scatter3_kernel<<<(3 * EE + 255) / 256, blk, 0, stream>>>(edges, rowptr3, cnt3, col3);
    }

    // lin1: h = lrelu(x @ lin1_W + b)   (x_bf in BIG; done before qhat overwrites)
    gemm_mfma<<<dim3(1, MT), blk, 0, stream>>>(
        x_bf, 768, x_bf, 768, KBIG, lin1Wt, lin1_b, h, 128, h_bf, 128, Nn, 768, 1);

    for (int l = 0; l < 2; l++) {
        int base = (l == 0) ? L0 : L1;
        const float* gb  = (const float*)d_in[base + 9];
        const float* sb1 = (const float*)d_in[base + 11];
        const float* sw2 = (const float*)d_in[base + 12];
        short* lWt4   = qkvsWt4 + (size_t)l * 245760;
        short* lgWt   = gWt + (size_t)l * 32768;
        short* lsW1t  = sW1t + (size_t)l * 65536;
        short* lwvst  = wvst + (size_t)l * 196608;
        float* lB4    = qkvsB4 + (size_t)l * 1920;
        float* lbvm   = bvmean + (size_t)l * 384;

        // qhat (3 rel) + U init (h@Ws+bs)
        gemm_qkvs_v4<<<dim3(15, MT), blk, 0, stream>>>(
            h_bf, lWt4, lB4, qhat3, U_bf, Nn);

        // attention in h-space: Ah = sum alpha * h[src]
        attn_v4<<<(3 * Nn + 3) / 4, blk, 0, stream>>>(qhat3, h_bf, rowptr3, col3, Ah3);

        // U += Ah @ Wvs/4 + mask*bvmean   [qhat3/Ah3 dead after this]
        ufin_mfma<<<dim3(1, MT, 3), blk, 0, stream>>>(Ah3, lwvst, lbvm, rowptr3, U_bf, Nn);

        // gate + combine (3 relations) -> Hm (fp32 + bf16)
        gate_mfma<<<dim3(1, MT, 3), blk, 0, stream>>>(
            U_bf, h_bf, lgWt, gb, h, Hm, Hm_bf, Nn);

        // semantic attention
        semantic_mfma<<<dim3(4, MT, 3), blk, 0, stream>>>(Hm_bf, lsW1t, sb1, sw2, partial, Nn);
        reduce12_kernel<<<12, 64, 0, stream>>>(partial, scores);
        compute_w_kernel<<<1, 64, 0, stream>>>(scores, wmix, 1.f / (float)Nn);
        mix_kernel<<<(Nn * 32 + 255) / 256, blk, 0, stream>>>(Hm, wmix, h, h_bf, Nn * 32);
    }

    // lin2 + lrelu -> lin2o (BIG region, Hm dead after mix)
    gemm_mfma<<<dim3(1, MT), blk, 0, stream>>>(
        h_bf, 128, h_bf, 128, KBIG, lin2Wt, lin2_b, lin2o, 128, (short*)nullptr, 0, Nn, 128, 1);
    clf_kernel<<<(Nn + 255) / 256, blk, 0, stream>>>(lin2o, clf_W, clf_b, out, Nn);
}

// Round 4
// 812.545 us; speedup vs baseline: 1.2471x; 1.1168x over previous
//
#include <hip/hip_runtime.h>
#include <math.h>

#define Nn 30000
#define RR 3
#define EE 80000
#define MT_M 235      // ceil(Nn/128)

#define SAP 72        // padded LDS row stride (bf16 elems) for staged tiles
#define EP_LD 68      // per-wave epilogue scratch stride (floats)
#define KBIG 0x40000000

typedef __attribute__((ext_vector_type(8))) short bf16x8;
typedef __attribute__((ext_vector_type(4))) float f32x4;

__device__ __forceinline__ unsigned short f2bf(float f) {
    union { float f; unsigned u; } v; v.f = f;
    unsigned r = v.u + 0x7fff + ((v.u >> 16) & 1);
    return (unsigned short)(r >> 16);
}
__device__ __forceinline__ float fast_tanh(float x) {
    float e = __expf(2.f * x);
    return 1.f - 2.f / (e + 1.f);
}
__device__ __forceinline__ void unpack8(uint4 u, float* f) {
    union { unsigned u; float f; } a;
    a.u = u.x << 16;          f[0] = a.f;
    a.u = u.x & 0xffff0000u;  f[1] = a.f;
    a.u = u.y << 16;          f[2] = a.f;
    a.u = u.y & 0xffff0000u;  f[3] = a.f;
    a.u = u.z << 16;          f[4] = a.f;
    a.u = u.z & 0xffff0000u;  f[5] = a.f;
    a.u = u.w << 16;          f[6] = a.f;
    a.u = u.w & 0xffff0000u;  f[7] = a.f;
}

// ---------------------------------------------------------------------------
// LDS-staged MFMA GEMM core (128x128 tile, BK=64, 4 waves x 64x64).
// ---------------------------------------------------------------------------
__device__ __forceinline__ void mfma_core(
    const short* __restrict__ A, int lda,
    const short* __restrict__ A2, int lda2, int ksplit,
    const short* __restrict__ Bt,
    int M, int K, int m0, int n0,
    short* As, short* Bs, f32x4 (&acc)[4][4])
{
    const int t = threadIdx.x;
    const int srow = t >> 3;          // 0..31
    const int scol = (t & 7) << 3;    // 0..56 step 8
    const int lane = t & 63;
    const int wave = t >> 6;
    const int wm = (wave >> 1) << 6;
    const int wn = (wave & 1) << 6;
    const int fr = lane & 15;
    const int quad = lane >> 4;

    for (int k0 = 0; k0 < K; k0 += 64) {
        const short* Abase; int kk0, ldax;
        if (k0 < ksplit) { Abase = A;  kk0 = k0;          ldax = lda;  }
        else             { Abase = A2; kk0 = k0 - ksplit; ldax = lda2; }
        #pragma unroll
        for (int rr = 0; rr < 4; rr++) {
            int r = srow + rr * 32;
            int gr = m0 + r;
            bf16x8 va = {0, 0, 0, 0, 0, 0, 0, 0};
            if (gr < M) va = *(const bf16x8*)(Abase + (size_t)gr * ldax + kk0 + scol);
            *(bf16x8*)(As + r * SAP + scol) = va;
        }
        #pragma unroll
        for (int rr = 0; rr < 4; rr++) {
            int r = srow + rr * 32;
            bf16x8 vb = *(const bf16x8*)(Bt + (size_t)(n0 + r) * K + k0 + scol);
            *(bf16x8*)(Bs + r * SAP + scol) = vb;
        }
        __syncthreads();
        #pragma unroll
        for (int kc = 0; kc < 2; kc++) {
            bf16x8 af[4], bfr[4];
            #pragma unroll
            for (int i = 0; i < 4; i++)
                af[i] = *(const bf16x8*)(As + (wm + i * 16 + fr) * SAP + kc * 32 + quad * 8);
            #pragma unroll
            for (int i = 0; i < 4; i++)
                bfr[i] = *(const bf16x8*)(Bs + (wn + i * 16 + fr) * SAP + kc * 32 + quad * 8);
            #pragma unroll
            for (int mi = 0; mi < 4; mi++)
                #pragma unroll
                for (int ni = 0; ni < 4; ni++)
                    acc[mi][ni] = __builtin_amdgcn_mfma_f32_16x16x32_bf16(
                        af[mi], bfr[ni], acc[mi][ni], 0, 0, 0);
        }
        __syncthreads();
    }
}

// General GEMM: C = act(A @ Bt^T + bias). Wave-private LDS repack epilogue.
__global__ __launch_bounds__(256) void gemm_mfma(
    const short* __restrict__ A, int lda,
    const short* __restrict__ A2, int lda2, int ksplit,
    const short* __restrict__ Bt, const float* __restrict__ bias,
    float* __restrict__ C, int ldc, short* __restrict__ Cbf, int ldcbf,
    int M, int K, int act)
{
    __shared__ short As[128 * SAP];
    __shared__ short Bs[128 * SAP];
    f32x4 acc[4][4];
    #pragma unroll
    for (int i = 0; i < 4; i++)
        #pragma unroll
        for (int j = 0; j < 4; j++) acc[i][j] = (f32x4){0.f, 0.f, 0.f, 0.f};
    int m0 = blockIdx.y * 128, n0 = blockIdx.x * 128;
    mfma_core(A, lda, A2, lda2, ksplit, Bt, M, K, m0, n0, As, Bs, acc);

    const int t = threadIdx.x;
    const int lane = t & 63, wave = t >> 6;
    const int wm = (wave >> 1) << 6, wn = (wave & 1) << 6;
    const int fr = lane & 15, quad = lane >> 4;
    float* ws = (float*)As + wave * 16 * EP_LD;   // wave-private (post-barrier)
    const int rrow = lane >> 2;
    const int cseg = (lane & 3) << 4;
    #pragma unroll
    for (int mi = 0; mi < 4; mi++) {
        #pragma unroll
        for (int ni = 0; ni < 4; ni++)
            #pragma unroll
            for (int reg = 0; reg < 4; reg++)
                ws[(quad * 4 + reg) * EP_LD + ni * 16 + fr] = acc[mi][ni][reg];
        int gr = m0 + wm + mi * 16 + rrow;
        if (gr >= M) continue;
        int gc = n0 + wn + cseg;
        float vals[16];
        #pragma unroll
        for (int j = 0; j < 16; j++) {
            float v = ws[rrow * EP_LD + cseg + j] + bias[gc + j];
            if (act == 1) v = (v >= 0.f) ? v : 0.01f * v;
            vals[j] = v;
        }
        if (C) {
            float* cp = C + (size_t)gr * ldc + gc;
            #pragma unroll
            for (int j4 = 0; j4 < 4; j4++)
                *(float4*)(cp + j4 * 4) = make_float4(vals[j4 * 4], vals[j4 * 4 + 1],
                                                      vals[j4 * 4 + 2], vals[j4 * 4 + 3]);
        }
        if (Cbf) {
            unsigned pk[8];
            #pragma unroll
            for (int j2 = 0; j2 < 8; j2++)
                pk[j2] = ((unsigned)f2bf(vals[2 * j2 + 1]) << 16) | (unsigned)f2bf(vals[2 * j2]);
            unsigned* bp = (unsigned*)(Cbf + (size_t)gr * ldcbf + gc);
            *(uint4*)bp       = make_uint4(pk[0], pk[1], pk[2], pk[3]);
            *(uint4*)(bp + 4) = make_uint4(pk[4], pk[5], pk[6], pk[7]);
        }
    }
}

// ---------------------------------------------------------------------------
// v4 fused projection: qhat (= h@G + c, scaled, 3 rel x 512) | U-init (h@Ws+bs).
// Wt4: [1920][128]; bias4 [1920].
//   bx<12: -> qhat3[r=bx/4][gr][(bx%4)*128+..]
//   bx>=12: -> Ubf[gr*384 + (bx-12)*128 + ..]
// ---------------------------------------------------------------------------
__global__ __launch_bounds__(256) void gemm_qkvs_v4(
    const short* __restrict__ A,       // h_bf [N,128]
    const short* __restrict__ Wt, const float* __restrict__ bias,
    short* __restrict__ qhat3, short* __restrict__ Ubf, int M)
{
    __shared__ short As[128 * SAP];
    __shared__ short Bs[128 * SAP];
    f32x4 acc[4][4];
    #pragma unroll
    for (int i = 0; i < 4; i++)
        #pragma unroll
        for (int j = 0; j < 4; j++) acc[i][j] = (f32x4){0.f, 0.f, 0.f, 0.f};
    int m0 = blockIdx.y * 128, bx = blockIdx.x, n0 = bx * 128;
    mfma_core(A, 128, A, 128, KBIG, Wt, M, 128, m0, n0, As, Bs, acc);

    const int t = threadIdx.x;
    const int lane = t & 63, wave = t >> 6;
    const int wm = (wave >> 1) << 6, wn = (wave & 1) << 6;
    const int fr = lane & 15, quad = lane >> 4;
    float* ws = (float*)As + wave * 16 * EP_LD;
    const int rrow = lane >> 2;
    const int cseg = (lane & 3) << 4;
    #pragma unroll
    for (int mi = 0; mi < 4; mi++) {
        #pragma unroll
        for (int ni = 0; ni < 4; ni++)
            #pragma unroll
            for (int reg = 0; reg < 4; reg++)
                ws[(quad * 4 + reg) * EP_LD + ni * 16 + fr] = acc[mi][ni][reg];
        int gr = m0 + wm + mi * 16 + rrow;
        if (gr >= M) continue;
        int lc = wn + cseg;               // 0..112 local col start
        float vals[16];
        #pragma unroll
        for (int j = 0; j < 16; j++)
            vals[j] = ws[rrow * EP_LD + cseg + j] + bias[n0 + lc + j];
        unsigned pk[8];
        #pragma unroll
        for (int j2 = 0; j2 < 8; j2++)
            pk[j2] = ((unsigned)f2bf(vals[2 * j2 + 1]) << 16) | (unsigned)f2bf(vals[2 * j2]);
        short* dst;
        if (bx < 12) {
            int r = bx >> 2;
            dst = qhat3 + ((size_t)(r * Nn + gr)) * 512 + (bx - r * 4) * 128 + lc;
        } else {
            dst = Ubf + (size_t)gr * 384 + (bx - 12) * 128 + lc;
        }
        unsigned* bp = (unsigned*)dst;
        *(uint4*)bp       = make_uint4(pk[0], pk[1], pk[2], pk[3]);
        *(uint4*)(bp + 4) = make_uint4(pk[4], pk[5], pk[6], pk[7]);
    }
}

// ---------------------------------------------------------------------------
// v4 attention: per (dst,rel) wave. logit[h] = qhat[dst,h*128:].h[src] (scale
// folded into qhat). Online softmax per 16-lane head group; accumulate
// Ah[h][128] = sum alpha*h[src]. Writes Ah3 [3][N][512] bf16.
// Gather = 256 B/edge from h_bf (7.7 MB, L2-resident).
// ---------------------------------------------------------------------------
__global__ __launch_bounds__(256) void attn_v4(
    const short* __restrict__ qhat3, const short* __restrict__ hbf,
    const int* __restrict__ rowptr3, const int* __restrict__ col3,
    short* __restrict__ Ah3)
{
    int wid = ((blockIdx.x * blockDim.x + threadIdx.x) >> 6);
    int lane = threadIdx.x & 63;
    if (wid >= 3 * Nn) return;
    int r = wid / Nn, n = wid - r * Nn;
    const int* rowptr = rowptr3 + r * (Nn + 1);
    const int* colb = col3 + r * EE;
    int beg = rowptr[n], end = rowptr[n + 1];

    uint4 qv = ((const uint4*)(qhat3 + ((size_t)r * Nn + n) * 512))[lane];
    float qf[8];
    unpack8(qv, qf);
    const int l16 = lane & 15;

    float m = -INFINITY, s = 0.f;
    float acc[8] = {0.f, 0.f, 0.f, 0.f, 0.f, 0.f, 0.f, 0.f};

    for (int i = beg; i < end; i++) {
        int src = colb[i];
        uint4 hv = ((const uint4*)(hbf + (size_t)src * 128))[l16];
        float hf[8];
        unpack8(hv, hf);
        float p = qf[0] * hf[0] + qf[1] * hf[1] + qf[2] * hf[2] + qf[3] * hf[3]
                + qf[4] * hf[4] + qf[5] * hf[5] + qf[6] * hf[6] + qf[7] * hf[7];
        p += __shfl_xor(p, 1);
        p += __shfl_xor(p, 2);
        p += __shfl_xor(p, 4);
        p += __shfl_xor(p, 8);
        float nm = fmaxf(m, p);
        float sc = __expf(m - nm);
        float pe = __expf(p - nm);
        s = s * sc + pe;
        #pragma unroll
        for (int j = 0; j < 8; j++) acc[j] = acc[j] * sc + pe * hf[j];
        m = nm;
    }

    float inv = (s > 0.f) ? 1.f / s : 0.f;
    #pragma unroll
    for (int j = 0; j < 8; j++) acc[j] *= inv;

    unsigned p0 = ((unsigned)f2bf(acc[1]) << 16) | (unsigned)f2bf(acc[0]);
    unsigned p1 = ((unsigned)f2bf(acc[3]) << 16) | (unsigned)f2bf(acc[2]);
    unsigned p2 = ((unsigned)f2bf(acc[5]) << 16) | (unsigned)f2bf(acc[4]);
    unsigned p3 = ((unsigned)f2bf(acc[7]) << 16) | (unsigned)f2bf(acc[6]);
    *(uint4*)(Ah3 + ((size_t)r * Nn + n) * 512 + lane * 8) = make_uint4(p0, p1, p2, p3);
}

// ---------------------------------------------------------------------------
// v4 U finalize: U_bf += Ah @ Wvs^T (1/4 folded) + mask*bvmean.  K=512.
// mask (edges exist) read from rowptr3. In-place on U_bf.
// ---------------------------------------------------------------------------
__global__ __launch_bounds__(256) void ufin_mfma(
    const short* __restrict__ Ah3, const short* __restrict__ wvst,
    const float* __restrict__ bvmean, const int* __restrict__ rowptr3,
    short* __restrict__ U_bf, int M)
{
    __shared__ short As[128 * SAP];
    __shared__ short Bs[128 * SAP];
    f32x4 acc[4][4];
    #pragma unroll
    for (int i = 0; i < 4; i++)
        #pragma unroll
        for (int j = 0; j < 4; j++) acc[i][j] = (f32x4){0.f, 0.f, 0.f, 0.f};
    int r = blockIdx.z;
    int m0 = blockIdx.y * 128;
    const short* Ar = Ah3 + (size_t)r * Nn * 512;
    mfma_core(Ar, 512, Ar, 512, KBIG, wvst + r * 65536, M, 512, m0, 0, As, Bs, acc);

    const int t = threadIdx.x;
    const int lane = t & 63, wave = t >> 6;
    const int wm = (wave >> 1) << 6, wn = (wave & 1) << 6;
    const int fr = lane & 15, quad = lane >> 4;
    float* ws = (float*)As + wave * 16 * EP_LD;
    const int rrow = lane >> 2;
    const int cseg = (lane & 3) << 4;
    #pragma unroll
    for (int mi = 0; mi < 4; mi++) {
        #pragma unroll
        for (int ni = 0; ni < 4; ni++)
            #pragma unroll
            for (int reg = 0; reg < 4; reg++)
                ws[(quad * 4 + reg) * EP_LD + ni * 16 + fr] = acc[mi][ni][reg];
        int gr = m0 + wm + mi * 16 + rrow;
        if (gr >= M) continue;
        int gc = wn + cseg;
        int be = rowptr3[r * (Nn + 1) + gr];
        int en = rowptr3[r * (Nn + 1) + gr + 1];
        float mk = (en > be) ? 1.f : 0.f;
        short* up = U_bf + (size_t)gr * 384 + r * 128 + gc;
        uint4 u0 = *(const uint4*)up;
        uint4 u1 = *(const uint4*)(up + 8);
        float uv[16];
        unpack8(u0, uv); unpack8(u1, uv + 8);
        float vals[16];
        #pragma unroll
        for (int j = 0; j < 16; j++)
            vals[j] = ws[rrow * EP_LD + cseg + j] + uv[j] + mk * bvmean[r * 128 + gc + j];
        unsigned pk[8];
        #pragma unroll
        for (int j2 = 0; j2 < 8; j2++)
            pk[j2] = ((unsigned)f2bf(vals[2 * j2 + 1]) << 16) | (unsigned)f2bf(vals[2 * j2]);
        unsigned* bp = (unsigned*)up;
        *(uint4*)bp       = make_uint4(pk[0], pk[1], pk[2], pk[3]);
        *(uint4*)(bp + 4) = make_uint4(pk[4], pk[5], pk[6], pk[7]);
    }
}

// Gate (z = relation): Z = sigmoid([U_r|h] @ gW + gb); Hm_r = tanh(U_r)*Z + h*(1-Z).
__global__ __launch_bounds__(256) void gate_mfma(
    const short* __restrict__ Ubf,   // [N,384] bf16
    const short* __restrict__ Hbf,   // [N,128] bf16
    const short* __restrict__ gWt, const float* __restrict__ gb,
    const float* __restrict__ Hf,    // [N,128] fp32
    float* __restrict__ Hm, short* __restrict__ HmBf,   // [N,384]
    int M)
{
    __shared__ short As[128 * SAP];
    __shared__ short Bs[128 * SAP];
    f32x4 acc[4][4];
    #pragma unroll
    for (int i = 0; i < 4; i++)
        #pragma unroll
        for (int j = 0; j < 4; j++) acc[i][j] = (f32x4){0.f, 0.f, 0.f, 0.f};
    int r = blockIdx.z;
    int m0 = blockIdx.y * 128;
    mfma_core(Ubf + r * 128, 384, Hbf, 128, 128, gWt, M, 256, m0, 0, As, Bs, acc);

    const int t = threadIdx.x;
    const int lane = t & 63, wave = t >> 6;
    const int wm = (wave >> 1) << 6, wn = (wave & 1) << 6;
    const int fr = lane & 15, quad = lane >> 4;
    float* ws = (float*)As + wave * 16 * EP_LD;
    const int rrow = lane >> 2;
    const int cseg = (lane & 3) << 4;
    #pragma unroll
    for (int mi = 0; mi < 4; mi++) {
        #pragma unroll
        for (int ni = 0; ni < 4; ni++)
            #pragma unroll
            for (int reg = 0; reg < 4; reg++)
                ws[(quad * 4 + reg) * EP_LD + ni * 16 + fr] = acc[mi][ni][reg];
        int gr = m0 + wm + mi * 16 + rrow;
        if (gr >= M) continue;
        int gc = wn + cseg;
        const short* up = Ubf + (size_t)gr * 384 + r * 128 + gc;
        const float* hp = Hf + (size_t)gr * 128 + gc;
        float uv[16], hv[16];
        uint4 u0 = *(const uint4*)up;
        uint4 u1 = *(const uint4*)(up + 8);
        unpack8(u0, uv); unpack8(u1, uv + 8);
        #pragma unroll
        for (int j4 = 0; j4 < 4; j4++)
            *(float4*)(hv + j4 * 4) = *(const float4*)(hp + j4 * 4);
        float vals[16];
        #pragma unroll
        for (int j = 0; j < 16; j++) {
            float g = ws[rrow * EP_LD + cseg + j] + gb[gc + j];
            float z = 1.f / (1.f + __expf(-g));
            vals[j] = fast_tanh(uv[j]) * z + hv[j] * (1.f - z);
        }
        float* cp = Hm + (size_t)gr * 384 + r * 128 + gc;
        #pragma unroll
        for (int j4 = 0; j4 < 4; j4++)
            *(float4*)(cp + j4 * 4) = make_float4(vals[j4 * 4], vals[j4 * 4 + 1],
                                                  vals[j4 * 4 + 2], vals[j4 * 4 + 3]);
        unsigned pk[8];
        #pragma unroll
        for (int j2 = 0; j2 < 8; j2++)
            pk[j2] = ((unsigned)f2bf(vals[2 * j2 + 1]) << 16) | (unsigned)f2bf(vals[2 * j2]);
        unsigned* bp = (unsigned*)(HmBf + (size_t)gr * 384 + r * 128 + gc);
        *(uint4*)bp       = make_uint4(pk[0], pk[1], pk[2], pk[3]);
        *(uint4*)(bp + 4) = make_uint4(pk[4], pk[5], pk[6], pk[7]);
    }
}

// Semantic partial sums (no atomics).
__global__ __launch_bounds__(256) void semantic_mfma(
    const short* __restrict__ HmBf, const short* __restrict__ sW1t,
    const float* __restrict__ sb1, const float* __restrict__ sw2,
    float* __restrict__ partial, int M)
{
    __shared__ short As[128 * SAP];
    __shared__ short Bs[128 * SAP];
    __shared__ float red4[4];
    f32x4 acc[4][4];
    #pragma unroll
    for (int i = 0; i < 4; i++)
        #pragma unroll
        for (int j = 0; j < 4; j++) acc[i][j] = (f32x4){0.f, 0.f, 0.f, 0.f};
    int head = blockIdx.x, r = blockIdx.z;
    int m0 = blockIdx.y * 128, n0 = head * 128;
    mfma_core(HmBf + r * 128, 384, HmBf + r * 128, 384, KBIG, sW1t, M, 128, m0, n0, As, Bs, acc);
    const int t = threadIdx.x;
    const int lane = t & 63, wave = t >> 6;
    const int wm = (wave >> 1) << 6, wn = (wave & 1) << 6;
    const int fr = lane & 15, quad = lane >> 4;
    float local = 0.f;
    #pragma unroll
    for (int ni = 0; ni < 4; ni++) {
        int gc = n0 + wn + ni * 16 + fr;
        float b = sb1[gc], w2 = sw2[gc];
        #pragma unroll
        for (int mi = 0; mi < 4; mi++) {
            #pragma unroll
            for (int reg = 0; reg < 4; reg++) {
                int gr = m0 + wm + mi * 16 + quad * 4 + reg;
                if (gr >= M) continue;
                local += fast_tanh(acc[mi][ni][reg] + b) * w2;
            }
        }
    }
    #pragma unroll
    for (int off = 1; off < 64; off <<= 1) local += __shfl_xor(local, off);
    if (lane == 0) red4[wave] = local;
    __syncthreads();
    if (t == 0)
        partial[(head * 3 + r) * MT_M + blockIdx.y] = red4[0] + red4[1] + red4[2] + red4[3];
}

__global__ void reduce12_kernel(const float* __restrict__ partial, float* __restrict__ scores)
{
    int z = blockIdx.x;
    int lane = threadIdx.x;   // 64 threads
    float s = 0.f;
    for (int i = lane; i < MT_M; i += 64) s += partial[z * MT_M + i];
    #pragma unroll
    for (int off = 1; off < 64; off <<= 1) s += __shfl_xor(s, off);
    if (lane == 0) scores[z] = s;
}

__global__ void compute_w_kernel(const float* __restrict__ scores, float* __restrict__ w, float invN)
{
    if (blockIdx.x == 0 && threadIdx.x == 0) {
        float wr[3] = {0.f, 0.f, 0.f};
        for (int h = 0; h < 4; h++) {
            float s0 = scores[h * 3 + 0] * invN;
            float s1 = scores[h * 3 + 1] * invN;
            float s2 = scores[h * 3 + 2] * invN;
            float mx = fmaxf(s0, fmaxf(s1, s2));
            float e0 = __expf(s0 - mx), e1 = __expf(s1 - mx), e2 = __expf(s2 - mx);
            float inv = 1.f / (e0 + e1 + e2);
            wr[0] += 0.25f * e0 * inv;
            wr[1] += 0.25f * e1 * inv;
            wr[2] += 0.25f * e2 * inv;
        }
        w[0] = wr[0]; w[1] = wr[1]; w[2] = wr[2];
    }
}

__global__ void mix_kernel(const float* __restrict__ Hm, const float* __restrict__ w,
                           float* __restrict__ h, short* __restrict__ hbf, int total4)
{
    int i = blockIdx.x * blockDim.x + threadIdx.x;
    if (i >= total4) return;
    int n = i >> 5, c4 = (i & 31) << 2;
    const float* row = Hm + (size_t)n * 384 + c4;
    float4 a = *(const float4*)row;
    float4 b = *(const float4*)(row + 128);
    float4 c = *(const float4*)(row + 256);
    float w0 = w[0], w1 = w[1], w2 = w[2];
    float4 v = make_float4(w0 * a.x + w1 * b.x + w2 * c.x,
                           w0 * a.y + w1 * b.y + w2 * c.y,
                           w0 * a.z + w1 * b.z + w2 * c.z,
                           w0 * a.w + w1 * b.w + w2 * c.w);
    *(float4*)(h + (size_t)n * 128 + c4) = v;
    unsigned p0 = ((unsigned)f2bf(v.y) << 16) | (unsigned)f2bf(v.x);
    unsigned p1 = ((unsigned)f2bf(v.w) << 16) | (unsigned)f2bf(v.z);
    *(uint2*)(hbf + (size_t)n * 128 + c4) = make_uint2(p0, p1);
}

// --------------------------- conversions -----------------------------------
__global__ void convert_bf16_kernel(const float* __restrict__ src, unsigned* __restrict__ dst, int n_pairs)
{
    int i = blockIdx.x * blockDim.x + threadIdx.x;
    if (i >= n_pairs) return;
    float2 f = ((const float2*)src)[i];
    dst[i] = ((unsigned)f2bf(f.y) << 16) | (unsigned)f2bf(f.x);
}

__global__ void prep_global_kernel(const float* __restrict__ lin1_W, const float* __restrict__ lin2_W,
                                   short* __restrict__ lin1Wt, short* __restrict__ lin2Wt)
{
    int id = blockIdx.x * blockDim.x + threadIdx.x;
    if (id < 98304) {
        int n = id / 768, k = id % 768;
        lin1Wt[id] = (short)f2bf(lin1_W[k * 128 + n]);
    } else if (id < 114688) {
        int r = id - 98304;
        int n = r / 128, k = r % 128;
        lin2Wt[r] = (short)f2bf(lin2_W[k * 128 + n]);
    }
}

// v4 per-layer prep (everything except G): Ws rows of Wt4, gWt, sW1t, wvst,
// bs bias, bvmean.  wvst[r][d][h*128+j] = Wv[r][j][h*128+d] / 4.
__global__ void prep_layer_v4(
    const float* __restrict__ Ws, const float* __restrict__ bs,
    const float* __restrict__ gW, const float* __restrict__ sW1,
    const float* __restrict__ Wv, const float* __restrict__ bv,
    short* __restrict__ Wt4, short* __restrict__ gWt,
    short* __restrict__ sW1t, short* __restrict__ wvst,
    float* __restrict__ B4, float* __restrict__ bvmean)
{
    const int S0 = 49152;              // Ws rows (384*128)
    const int S1 = S0 + 32768;         // gWt
    const int S2 = S1 + 65536;         // sW1t
    const int S3 = S2 + 196608;        // wvst [3][128][512]
    const int S4 = S3 + 384;           // bs
    const int S5 = S4 + 384;           // bvmean
    int id = blockIdx.x * blockDim.x + threadIdx.x;
    if (id < S0) {
        int n = id / 128, k = id - n * 128;
        int r = n >> 7, c = n & 127;
        Wt4[(size_t)(1536 + n) * 128 + k] = (short)f2bf(Ws[(size_t)r * 16384 + k * 128 + c]);
    } else if (id < S1) {
        int q = id - S0;
        int n = q / 256, k = q - n * 256;
        gWt[q] = (short)f2bf(gW[k * 128 + n]);
    } else if (id < S2) {
        int q = id - S1;
        int h = q / 16384, rem = q - h * 16384;
        int n = rem / 128, k = rem - n * 128;
        sW1t[q] = (short)f2bf(sW1[(size_t)h * 16384 + k * 128 + n]);
    } else if (id < S3) {
        int q = id - S2;
        int r = q / 65536, rem = q - r * 65536;
        int d = rem / 512, mcol = rem - d * 512;
        int hh = mcol >> 7, j = mcol & 127;
        wvst[q] = (short)f2bf(0.25f * Wv[(size_t)r * 65536 + j * 512 + hh * 128 + d]);
    } else if (id < S4) {
        int q = id - S3;
        B4[1536 + q] = bs[q];
    } else if (id < S5) {
        int q = id - S4;           // r*128 + d
        int r = q >> 7, d = q & 127;
        bvmean[q] = 0.25f * (bv[r * 512 + d] + bv[r * 512 + 128 + d]
                           + bv[r * 512 + 256 + d] + bv[r * 512 + 384 + d]);
    }
}

// ---------------------------------------------------------------------------
// G precompute v2: parallel + bank-safe. Grid (8 jg, 4 h, 6 lz) = 192 blocks.
// Block: stage Wq h-block [128][129] (pad->2-way free) + 16 Wk rows; each
// thread owns (i = t&127, 8 j's); fp32 d-loop in the SAME order as v4's
// gmat (bit-identical results). Writes G rows r*512+h*128+j of Wt4 and
// bias c[j] = scale*(Wk_j . bq_h).
// ---------------------------------------------------------------------------
__global__ __launch_bounds__(256) void gmat_v2(
    const float* __restrict__ Wq0, const float* __restrict__ Wk0, const float* __restrict__ bq0,
    const float* __restrict__ Wq1, const float* __restrict__ Wk1, const float* __restrict__ bq1,
    short* __restrict__ Wt4, float* __restrict__ B4)
{
    __shared__ float WqL[128 * 129];   // [i][d], pad 129 -> lane-i reads 2-way
    __shared__ float WkL[16 * 128];    // [jl][d], broadcast reads
    const int jg = blockIdx.x;         // 0..7 (16 j's each)
    const int h  = blockIdx.y;         // 0..3
    const int lz = blockIdx.z;         // 0..5
    const int l = lz / 3, r = lz - l * 3;
    const float* Wq = l ? Wq1 : Wq0;
    const float* Wk = l ? Wk1 : Wk0;
    const float* bq = l ? bq1 : bq0;
    short* Wt = Wt4 + (size_t)l * 245760;
    float* Bb = B4 + l * 1920;
    const float scale = 0.088388347648318447f;   // 1/sqrt(128)
    const int t = threadIdx.x;

    // stage Wq h-block: coalesced float4 rows -> padded LDS
    for (int v = t; v < 4096; v += 256) {
        int i = v >> 5, d4 = (v & 31) << 2;
        float4 q = *(const float4*)(Wq + (size_t)r * 65536 + i * 512 + h * 128 + d4);
        float* wp = WqL + i * 129 + d4;
        wp[0] = q.x; wp[1] = q.y; wp[2] = q.z; wp[3] = q.w;
    }
    // stage 16 Wk rows
    for (int v = t; v < 512; v += 256) {
        int jl = v >> 5, d4 = (v & 31) << 2;
        float4 q = *(const float4*)(Wk + (size_t)r * 65536 + (jg * 16 + jl) * 512 + h * 128 + d4);
        float* wp = WkL + jl * 128 + d4;
        wp[0] = q.x; wp[1] = q.y; wp[2] = q.z; wp[3] = q.w;
    }
    __syncthreads();

    const int i = t & 127;
    const int jh = t >> 7;             // 0/1 (wave-uniform)
    const float* wk = WkL + jh * 8 * 128;
    float acc[8] = {0.f, 0.f, 0.f, 0.f, 0.f, 0.f, 0.f, 0.f};
    #pragma unroll 4
    for (int d = 0; d < 128; d++) {
        float wq = WqL[i * 129 + d];
        #pragma unroll
        for (int jj = 0; jj < 8; jj++)
            acc[jj] += wq * wk[jj * 128 + d];
    }
    short* wrow = Wt + ((size_t)(r * 512 + h * 128 + jg * 16 + jh * 8)) * 128 + i;
    #pragma unroll
    for (int jj = 0; jj < 8; jj++)
        wrow[(size_t)jj * 128] = (short)f2bf(scale * acc[jj]);

    // bias c[j] for this block's 16 j's
    if (t < 16) {
        const float* bqh = bq + r * 512 + h * 128;
        float c = 0.f;
        for (int d = 0; d < 128; d++) c += bqh[d] * WkL[t * 128 + d];
        Bb[r * 512 + h * 128 + jg * 16 + t] = scale * c;
    }
}

// --------------------------- CSR build (once) ------------------------------
__global__ void zero_i32_kernel(int* __restrict__ p, int n)
{
    int i = blockIdx.x * blockDim.x + threadIdx.x;
    if (i < n) p[i] = 0;
}

__global__ void hist3_kernel(const int* __restrict__ edges, int* __restrict__ cnt3)
{
    int i = blockIdx.x * blockDim.x + threadIdx.x;
    if (i >= 3 * EE) return;
    int r = i / EE, e = i - r * EE;
    int d = edges[(size_t)r * 2 * EE + EE + e];
    atomicAdd(&cnt3[r * Nn + d], 1);
}

__global__ __launch_bounds__(1024) void scan3_kernel(const int* __restrict__ cnt3,
                                                     int* __restrict__ rowptr3)
{
    __shared__ int part[1024];
    const int r = blockIdx.x;
    const int* cnt = cnt3 + r * Nn;
    int* rowptr = rowptr3 + r * (Nn + 1);
    int tid = threadIdx.x;
    int per = (Nn + 1023) >> 10;
    int base = tid * per;
    int s = 0;
    for (int i = 0; i < per; i++) {
        int idx = base + i;
        if (idx < Nn) s += cnt[idx];
    }
    part[tid] = s;
    __syncthreads();
    for (int off = 1; off < 1024; off <<= 1) {
        int val = (tid >= off) ? part[tid - off] : 0;
        __syncthreads();
        part[tid] += val;
        __syncthreads();
    }
    int excl = (tid == 0) ? 0 : part[tid - 1];
    for (int i = 0; i < per; i++) {
        int idx = base + i;
        if (idx < Nn) { rowptr[idx] = excl; excl += cnt[idx]; }
    }
    if (tid == 1023) rowptr[Nn] = part[1023];
}

__global__ void scatter3_kernel(const int* __restrict__ edges,
                                const int* __restrict__ rowptr3, int* __restrict__ fill3,
                                int* __restrict__ col3)
{
    int i = blockIdx.x * blockDim.x + threadIdx.x;
    if (i >= 3 * EE) return;
    int r = i / EE, e = i - r * EE;
    int src = edges[(size_t)r * 2 * EE + e];
    int d   = edges[(size_t)r * 2 * EE + EE + e];
    int pos = rowptr3[r * (Nn + 1) + d] + atomicAdd(&fill3[r * Nn + d], 1);
    col3[r * EE + pos] = src;
}

// --------------------------- classifier -----------------------------------
__global__ void clf_kernel(const float* __restrict__ t, const float* __restrict__ W,
                           const float* __restrict__ b, float* __restrict__ out, int M)
{
    int n = blockIdx.x * blockDim.x + threadIdx.x;
    if (n >= M) return;
    const float* row = t + (size_t)n * 128;
    float a0 = b[0], a1 = b[1];
    #pragma unroll
    for (int kk = 0; kk < 128; kk++) {
        float a = row[kk];
        a0 += a * W[kk * 2];
        a1 += a * W[kk * 2 + 1];
    }
    out[n * 2] = a0;
    out[n * 2 + 1] = a1;
}

// ---------------------------------------------------------------------------
extern "C" void kernel_launch(void* const* d_in, const int* in_sizes, int n_in,
                              void* d_out, int out_size, void* d_ws, size_t ws_size,
                              hipStream_t stream)
{
    const float* x      = (const float*)d_in[0];
    const int*   edges  = (const int*)d_in[1];
    const float* lin1_W = (const float*)d_in[2];
    const float* lin1_b = (const float*)d_in[3];
    const int L0 = 4, L1 = 17;
    const float* lin2_W = (const float*)d_in[30];
    const float* lin2_b = (const float*)d_in[31];
    const float* clf_W  = (const float*)d_in[32];
    const float* clf_b  = (const float*)d_in[33];
    float* out = (float*)d_out;

    char* w = (char*)d_ws;
    size_t off = 0;
    auto alloc = [&](size_t bytes) { void* p = w + off; off = (off + bytes + 255) & ~(size_t)255; return p; };
    float* h      = (float*)alloc((size_t)Nn * 128 * 4);     // 15.4 MB
    short* h_bf   = (short*)alloc((size_t)Nn * 128 * 2);     //  7.7 MB
    short* U_bf   = (short*)alloc((size_t)Nn * 384 * 2);     // 23.0 MB
    // BIG union (184.3 MB): qhat3 [3][N][512] + Ah3 [3][N][512] bf16
    //   <-> x_bf [N,768] bf16  <-> Hm [N,384] f32 + Hm_bf [N,384] bf16 <-> lin2o
    const size_t QH = (size_t)3 * Nn * 512 * 2;
    char* BIG     = (char*)alloc(2 * QH);
    short* qhat3  = (short*)BIG;
    short* Ah3    = (short*)(BIG + QH);
    short* x_bf   = (short*)BIG;
    float* Hm     = (float*)BIG;
    short* Hm_bf  = (short*)(BIG + (size_t)Nn * 384 * 4);
    float* lin2o  = (float*)BIG;
    short* lin1Wt = (short*)alloc((size_t)98304 * 2);
    short* lin2Wt = (short*)alloc((size_t)16384 * 2);
    short* qkvsWt4 = (short*)alloc((size_t)2 * 245760 * 2);  // [layer][1920][128]
    short* gWt    = (short*)alloc((size_t)2 * 32768 * 2);
    short* sW1t   = (short*)alloc((size_t)2 * 65536 * 2);
    short* wvst   = (short*)alloc((size_t)2 * 196608 * 2);   // [layer][3][128][512]
    float* qkvsB4 = (float*)alloc((size_t)2 * 1920 * 4);
    float* bvmean = (float*)alloc((size_t)2 * 384 * 4);
    int* rowptr3  = (int*)alloc((size_t)3 * (Nn + 1) * 4);
    int* cnt3     = (int*)alloc((size_t)3 * Nn * 4);
    int* col3     = (int*)alloc((size_t)3 * EE * 4);
    float* partial = (float*)alloc((size_t)12 * MT_M * 4);
    float* scores = (float*)alloc(12 * 4);
    float* wmix   = (float*)alloc(3 * 4);

    const int MT = MT_M;    // 235
    dim3 blk(256);

    // ---- prep ----
    {
        int n_pairs = Nn * 768 / 2;
        convert_bf16_kernel<<<(n_pairs + 255) / 256, blk, 0, stream>>>(x, (unsigned*)x_bf, n_pairs);
        prep_global_kernel<<<(114688 + 255) / 256, blk, 0, stream>>>(lin1_W, lin2_W, lin1Wt, lin2Wt);
        for (int l = 0; l < 2; l++) {
            int base = (l == 0) ? L0 : L1;
            prep_layer_v4<<<(344832 + 255) / 256, blk, 0, stream>>>(
                (const float*)d_in[base + 6], (const float*)d_in[base + 7],
                (const float*)d_in[base + 8], (const float*)d_in[base + 10],
                (const float*)d_in[base + 4], (const float*)d_in[base + 5],
                qkvsWt4 + (size_t)l * 245760, gWt + (size_t)l * 32768,
                sW1t + (size_t)l * 65536, wvst + (size_t)l * 196608,
                qkvsB4 + (size_t)l * 1920, bvmean + (size_t)l * 384);
        }
        gmat_v2<<<dim3(8, 4, 6), blk, 0, stream>>>(
            (const float*)d_in[L0 + 0], (const float*)d_in[L0 + 2], (const float*)d_in[L0 + 1],
            (const float*)d_in[L1 + 0], (const float*)d_in[L1 + 2], (const float*)d_in[L1 + 1],
            qkvsWt4, qkvsB4);
        zero_i32_kernel<<<(3 * Nn + 255) / 256, blk, 0, stream>>>(cnt3, 3 * Nn);
        hist3_kernel<<<(3 * EE + 255) / 256, blk, 0, stream>>>(edges, cnt3);
        scan3_kernel<<<3, 1024, 0, stream>>>(cnt3, rowptr3);
        zero_i32_kernel<<<(3 * Nn + 255) / 256, blk, 0, stream>>>(cnt3, 3 * Nn);
        scatter3_kernel<<<(3 * EE + 255) / 256, blk, 0, stream>>>(edges, rowptr3, cnt3, col3);
    }

    // lin1: h = lrelu(x @ lin1_W + b)   (x_bf in BIG; done before qhat overwrites)
    gemm_mfma<<<dim3(1, MT), blk, 0, stream>>>(
        x_bf, 768, x_bf, 768, KBIG, lin1Wt, lin1_b, h, 128, h_bf, 128, Nn, 768, 1);

    for (int l = 0; l < 2; l++) {
        int base = (l == 0) ? L0 : L1;
        const float* gb  = (const float*)d_in[base + 9];
        const float* sb1 = (const float*)d_in[base + 11];
        const float* sw2 = (const float*)d_in[base + 12];
        short* lWt4   = qkvsWt4 + (size_t)l * 245760;
        short* lgWt   = gWt + (size_t)l * 32768;
        short* lsW1t  = sW1t + (size_t)l * 65536;
        short* lwvst  = wvst + (size_t)l * 196608;
        float* lB4    = qkvsB4 + (size_t)l * 1920;
        float* lbvm   = bvmean + (size_t)l * 384;

        // qhat (3 rel) + U init (h@Ws+bs)
        gemm_qkvs_v4<<<dim3(15, MT), blk, 0, stream>>>(
            h_bf, lWt4, lB4, qhat3, U_bf, Nn);

        // attention in h-space: Ah = sum alpha * h[src]
        attn_v4<<<(3 * Nn + 3) / 4, blk, 0, stream>>>(qhat3, h_bf, rowptr3, col3, Ah3);

        // U += Ah @ Wvs/4 + mask*bvmean   [qhat3/Ah3 dead after this]
        ufin_mfma<<<dim3(1, MT, 3), blk, 0, stream>>>(Ah3, lwvst, lbvm, rowptr3, U_bf, Nn);

        // gate + combine (3 relations) -> Hm (fp32 + bf16)
        gate_mfma<<<dim3(1, MT, 3), blk, 0, stream>>>(
            U_bf, h_bf, lgWt, gb, h, Hm, Hm_bf, Nn);

        // semantic attention
        semantic_mfma<<<dim3(4, MT, 3), blk, 0, stream>>>(Hm_bf, lsW1t, sb1, sw2, partial, Nn);
        reduce12_kernel<<<12, 64, 0, stream>>>(partial, scores);
        compute_w_kernel<<<1, 64, 0, stream>>>(scores, wmix, 1.f / (float)Nn);
        mix_kernel<<<(Nn * 32 + 255) / 256, blk, 0, stream>>>(Hm, wmix, h, h_bf, Nn * 32);
    }

    // lin2 + lrelu -> lin2o (BIG region, Hm dead after mix)
    gemm_mfma<<<dim3(1, MT), blk, 0, stream>>>(
        h_bf, 128, h_bf, 128, KBIG, lin2Wt, lin2_b, lin2o, 128, (short*)nullptr, 0, Nn, 128, 1);
    clf_kernel<<<(Nn + 255) / 256, blk, 0, stream>>>(lin2o, clf_W, clf_b, out, Nn);
}